// Round 3
// baseline (255.356 us; speedup 1.0000x reference)
//
#include <hip/hip_runtime.h>

// Problem constants
#define B_  2
#define N_  320
#define D_  512
#define H_  8
#define DH_ 64
#define ED_ 64

typedef __attribute__((ext_vector_type(8))) short bf16x8;
typedef __attribute__((ext_vector_type(4))) float floatx4;

__device__ __forceinline__ ushort f2bf(float f) {
    union { float f; unsigned u; } c; c.f = f;
    unsigned u = c.u;
    return (ushort)((u + 0x7fffu + ((u >> 16) & 1u)) >> 16);
}
__device__ __forceinline__ float bf2f(ushort s) {
    union { unsigned u; float f; } c; c.u = ((unsigned)s) << 16;
    return c.f;
}

// ------------------------------------------------------------------
// bf16 MFMA GEMM: C = A[M,K] @ W[K,N] + bias.  BM=BN=64, BK=32,
// 256 threads = 4 waves (2x2), each wave 32x32 = 2x2 frags of 16x16.
// MODE 0: C0[row*N+col].  MODE 1 (kv): col<512 -> k_t[b][col][i],
//                                      col>=512 -> v[b*320+i][col-512].
// ------------------------------------------------------------------
template <int MODE>
__global__ __launch_bounds__(256) void gemm_bf16(
    const float* __restrict__ A, const float* __restrict__ W,
    const float* __restrict__ bias, float* __restrict__ C0,
    float* __restrict__ C1, int N, int K)
{
    __shared__ short As[64 * 56];   // [m][k], stride 56 (112B, 16B-mult)
    __shared__ short Ws[64 * 56];   // [col][k] (transposed)
    const int tid  = threadIdx.x;
    const int lane = tid & 63;
    const int wid  = tid >> 6;
    const int wr   = wid >> 1, wc = wid & 1;
    const int bm   = blockIdx.x * 64, bn = blockIdx.y * 64;
    const int srow = tid >> 2;         // 0..63
    const int skg  = (tid & 3) * 8;    // 0,8,16,24

    floatx4 acc[2][2] = {};

    for (int k0 = 0; k0 < K; k0 += 32) {
        {   // stage A (64x32) as bf16
            const float* src = A + (long)(bm + srow) * K + (k0 + skg);
            float4 lo = *(const float4*)src;
            float4 hi = *(const float4*)(src + 4);
            bf16x8 pk;
            pk[0] = (short)f2bf(lo.x); pk[1] = (short)f2bf(lo.y);
            pk[2] = (short)f2bf(lo.z); pk[3] = (short)f2bf(lo.w);
            pk[4] = (short)f2bf(hi.x); pk[5] = (short)f2bf(hi.y);
            pk[6] = (short)f2bf(hi.z); pk[7] = (short)f2bf(hi.w);
            *(bf16x8*)&As[srow * 56 + skg] = pk;
        }
        {   // stage W (32x64) transposed -> Ws[col][k]
            const float* src = W + (long)(k0 + skg) * N + (bn + srow);
            bf16x8 pk;
            #pragma unroll
            for (int e = 0; e < 8; ++e) pk[e] = (short)f2bf(src[(long)e * N]);
            *(bf16x8*)&Ws[srow * 56 + skg] = pk;
        }
        __syncthreads();
        const int r16 = lane & 15, kc = (lane >> 4) * 8;
        bf16x8 af[2], wf[2];
        #pragma unroll
        for (int mf = 0; mf < 2; ++mf)
            af[mf] = *(const bf16x8*)&As[(wr * 32 + mf * 16 + r16) * 56 + kc];
        #pragma unroll
        for (int nf = 0; nf < 2; ++nf)
            wf[nf] = *(const bf16x8*)&Ws[(wc * 32 + nf * 16 + r16) * 56 + kc];
        #pragma unroll
        for (int mf = 0; mf < 2; ++mf)
            #pragma unroll
            for (int nf = 0; nf < 2; ++nf)
                acc[mf][nf] = __builtin_amdgcn_mfma_f32_16x16x32_bf16(
                    af[mf], wf[nf], acc[mf][nf], 0, 0, 0);
        __syncthreads();
    }

    // epilogue: D lane map (verified m89): col=lane&15, row=(lane>>4)*4+j
    const int r4 = (lane >> 4) * 4, c16 = lane & 15;
    #pragma unroll
    for (int mf = 0; mf < 2; ++mf)
        #pragma unroll
        for (int nf = 0; nf < 2; ++nf)
            #pragma unroll
            for (int j = 0; j < 4; ++j) {
                int row = bm + wr * 32 + mf * 16 + r4 + j;
                int col = bn + wc * 32 + nf * 16 + c16;
                float val = acc[mf][nf][j] + bias[col];
                if (MODE == 0) {
                    C0[(long)row * N + col] = val;
                } else {
                    if (col < 512) {
                        int bb = row / N_, ii = row % N_;
                        C0[((long)bb * 512 + col) * N_ + ii] = val;   // k_t[b][hd][n]
                    } else {
                        C1[(long)row * 512 + (col - 512)] = val;      // v[b][n][hd]
                    }
                }
            }
}

// ------------------------------------------------------------------
// f32 tiled GEMM for the final projection (keeps output rounding f32).
// BM=BN=64, BK=16, 256 threads, 4x4 micro-tile per thread.
// ------------------------------------------------------------------
__global__ __launch_bounds__(256) void gemm_f32(
    const float* __restrict__ A, const float* __restrict__ W,
    const float* __restrict__ bias, float* __restrict__ C, int N, int K)
{
    __shared__ float As[64][17];
    __shared__ float Bs[16][68];
    const int tid = threadIdx.x;
    const int bm = blockIdx.x * 64, bn = blockIdx.y * 64;
    const int ty = tid >> 4, tx = tid & 15;
    float acc[4][4] = {};
    for (int k0 = 0; k0 < K; k0 += 16) {
        {
            int m = tid >> 2, kk = (tid & 3) * 4;
            float4 a4 = *(const float4*)&A[(long)(bm + m) * K + k0 + kk];
            As[m][kk] = a4.x; As[m][kk + 1] = a4.y; As[m][kk + 2] = a4.z; As[m][kk + 3] = a4.w;
        }
        {
            int kk = tid >> 4, n4 = (tid & 15) * 4;
            float4 b4 = *(const float4*)&W[(long)(k0 + kk) * N + bn + n4];
            Bs[kk][n4] = b4.x; Bs[kk][n4 + 1] = b4.y; Bs[kk][n4 + 2] = b4.z; Bs[kk][n4 + 3] = b4.w;
        }
        __syncthreads();
        #pragma unroll
        for (int k = 0; k < 16; ++k) {
            float a0 = As[ty * 4 + 0][k], a1 = As[ty * 4 + 1][k],
                  a2 = As[ty * 4 + 2][k], a3 = As[ty * 4 + 3][k];
            float b0 = Bs[k][tx * 4 + 0], b1 = Bs[k][tx * 4 + 1],
                  b2 = Bs[k][tx * 4 + 2], b3 = Bs[k][tx * 4 + 3];
            acc[0][0] += a0 * b0; acc[0][1] += a0 * b1; acc[0][2] += a0 * b2; acc[0][3] += a0 * b3;
            acc[1][0] += a1 * b0; acc[1][1] += a1 * b1; acc[1][2] += a1 * b2; acc[1][3] += a1 * b3;
            acc[2][0] += a2 * b0; acc[2][1] += a2 * b1; acc[2][2] += a2 * b2; acc[2][3] += a2 * b3;
            acc[3][0] += a3 * b0; acc[3][1] += a3 * b1; acc[3][2] += a3 * b2; acc[3][3] += a3 * b3;
        }
        __syncthreads();
    }
    #pragma unroll
    for (int r = 0; r < 4; ++r)
        #pragma unroll
        for (int c = 0; c < 4; ++c)
            C[(long)(bm + ty * 4 + r) * N + bn + tx * 4 + c] =
                acc[r][c] + bias[bn + tx * 4 + c];
}

// ------------------------------------------------------------------
// t[b,i,h,c] = sum_d q[b,i,h*64+d] * W_e[c, h*64+d]
// grid 640 (=b*320+i), 512 threads: thread -> (h=t>>6, c=t&63)
// ------------------------------------------------------------------
__global__ __launch_bounds__(512) void t_kernel(
    const float* __restrict__ q, const float* __restrict__ W_e,
    float* __restrict__ t_out)
{
    __shared__ float q_lds[512];
    const int blk = blockIdx.x, tid = threadIdx.x;
    q_lds[tid] = q[(long)blk * 512 + tid];
    __syncthreads();
    const int h = tid >> 6, c = tid & 63;
    const float4* w4 = (const float4*)(W_e + (long)c * 512 + h * 64);
    const float4* q4 = (const float4*)(q_lds + h * 64);
    float acc = 0.f;
    #pragma unroll
    for (int d = 0; d < 16; ++d) {
        float4 a = q4[d], b = w4[d];
        acc += a.x * b.x + a.y * b.y + a.z * b.z + a.w * b.w;
    }
    t_out[(long)blk * 512 + tid] = acc;   // [blk][h*64+c]
}

// ------------------------------------------------------------------
// Fused attention per (b,i): 512 threads = 8 waves, wave w == head w.
//  S[w][j] = ( q_i[w,:].k[j,w,:] + t_i[w,:].E[:,j] ) * 1/8
//  A = softmax_j(S);  O = A@v_head + (A@E^T)@W_e_head + b_e
// E (edges[b,:,i,:]) staged once in LDS as bf16 [64][324] (pad: 648B rows,
// dword-stride 162 == 2 mod 32 -> conflict-free row reads in phase 3).
// ------------------------------------------------------------------
__global__ __launch_bounds__(512) void attn_kernel(
    const float* __restrict__ q, const float* __restrict__ k_t,
    const float* __restrict__ v, const float* __restrict__ t_in,
    const float* __restrict__ edges, const float* __restrict__ W_e,
    const float* __restrict__ b_e, float* __restrict__ o_out)
{
    __shared__ ushort E_s[64 * 324];   // 41.5 KB bf16
    __shared__ float  A_lds[8 * 320];  // 10.25 KB
    __shared__ float  q_lds[512];
    __shared__ float  t_lds[512];
    __shared__ float  U_lds[512];

    const int blk = blockIdx.x;
    const int b = blk / N_, i = blk % N_;
    const int tid = threadIdx.x;
    const int w = tid >> 6, lane = tid & 63;

    q_lds[tid] = q[(long)blk * 512 + tid];
    t_lds[tid] = t_in[(long)blk * 512 + tid];
    {   // E load: edges[b][c][i][j], float2 -> 2 bf16 per store
        const float* ebase = edges + (long)b * ED_ * N_ * N_ + (long)i * N_;
        for (int idx = tid; idx < 64 * 160; idx += 512) {
            int c = idx / 160, jj = (idx % 160) * 2;
            float2 e2 = *(const float2*)(ebase + (long)c * (N_ * N_) + jj);
            unsigned lo = f2bf(e2.x), hi = f2bf(e2.y);
            *(unsigned*)&E_s[c * 324 + jj] = lo | (hi << 16);
        }
    }
    __syncthreads();

    // ---- Phase 1: S for this wave's head (lane j, 5 j-tiles of 64) ----
    float sacc[5] = {0.f, 0.f, 0.f, 0.f, 0.f};
    {
        const float* tl = t_lds + w * 64;
        #pragma unroll 4
        for (int c = 0; c < 64; ++c) {
            float tc = tl[c];
            const ushort* er = &E_s[c * 324 + lane];
            sacc[0] += tc * bf2f(er[0]);
            sacc[1] += tc * bf2f(er[64]);
            sacc[2] += tc * bf2f(er[128]);
            sacc[3] += tc * bf2f(er[192]);
            sacc[4] += tc * bf2f(er[256]);
        }
        const float* ql = q_lds + w * 64;
        const float* kb = k_t + ((long)b * 512 + w * 64) * N_;
        #pragma unroll 4
        for (int d = 0; d < 64; ++d) {
            float qd = ql[d];
            const float* kr = kb + (long)d * N_ + lane;
            sacc[0] += qd * kr[0];
            sacc[1] += qd * kr[64];
            sacc[2] += qd * kr[128];
            sacc[3] += qd * kr[192];
            sacc[4] += qd * kr[256];
        }
    }
    const float scale = 0.125f;   // 64^-0.5
    float s0 = sacc[0] * scale, s1 = sacc[1] * scale, s2 = sacc[2] * scale,
          s3 = sacc[3] * scale, s4 = sacc[4] * scale;

    // ---- Phase 2: in-wave softmax over 320 ----
    float m = fmaxf(fmaxf(fmaxf(s0, s1), fmaxf(s2, s3)), s4);
    #pragma unroll
    for (int off = 32; off >= 1; off >>= 1) m = fmaxf(m, __shfl_xor(m, off, 64));
    s0 = __expf(s0 - m); s1 = __expf(s1 - m); s2 = __expf(s2 - m);
    s3 = __expf(s3 - m); s4 = __expf(s4 - m);
    float sum = s0 + s1 + s2 + s3 + s4;
    #pragma unroll
    for (int off = 32; off >= 1; off >>= 1) sum += __shfl_xor(sum, off, 64);
    float inv = 1.f / sum;
    A_lds[w * 320 + lane]       = s0 * inv;
    A_lds[w * 320 + 64 + lane]  = s1 * inv;
    A_lds[w * 320 + 128 + lane] = s2 * inv;
    A_lds[w * 320 + 192 + lane] = s3 * inv;
    A_lds[w * 320 + 256 + lane] = s4 * inv;
    __syncthreads();

    // ---- Phase 3: O_v[w][lane] and U[w][lane] (lane = d and c) ----
    float acc_v = 0.f, acc_u = 0.f;
    {
        const float*  vb = v + (long)b * N_ * 512 + w * 64 + lane;
        const ushort* Er = E_s + lane * 324;
        const float*  Ar = A_lds + w * 320;
        #pragma unroll 4
        for (int j4 = 0; j4 < 80; ++j4) {
            float4 a4 = *(const float4*)&Ar[j4 * 4];
            uint2  e2 = *(const uint2*)&Er[j4 * 4];
            float e0 = bf2f((ushort)(e2.x & 0xffffu));
            float e1 = bf2f((ushort)(e2.x >> 16));
            float e2f = bf2f((ushort)(e2.y & 0xffffu));
            float e3 = bf2f((ushort)(e2.y >> 16));
            const float* vv = vb + (long)j4 * 4 * 512;
            acc_v += a4.x * vv[0] + a4.y * vv[512] + a4.z * vv[1024] + a4.w * vv[1536];
            acc_u += a4.x * e0 + a4.y * e1 + a4.z * e2f + a4.w * e3;
        }
    }
    U_lds[w * 64 + lane] = acc_u;
    __syncthreads();

    // ---- Phase 4: project U through W_e_head, add b_e, write o ----
    float o_val = acc_v + b_e[w * 64 + lane];
    {
        const float* wb = W_e + w * 64 + lane;
        const float* Ur = U_lds + w * 64;
        #pragma unroll 8
        for (int c = 0; c < 64; ++c)
            o_val += Ur[c] * wb[(long)c * 512];
    }
    o_out[(long)blk * 512 + w * 64 + lane] = o_val;
}

// ------------------------------------------------------------------
extern "C" void kernel_launch(void* const* d_in, const int* in_sizes, int n_in,
                              void* d_out, int out_size, void* d_ws, size_t ws_size,
                              hipStream_t stream)
{
    const float* nodes = (const float*)d_in[0];
    const float* edges = (const float*)d_in[1];
    const float* W_exp = (const float*)d_in[2];
    const float* b_exp = (const float*)d_in[3];
    const float* W_q   = (const float*)d_in[4];
    const float* b_q   = (const float*)d_in[5];
    const float* W_kv  = (const float*)d_in[6];
    const float* b_kv  = (const float*)d_in[7];
    const float* W_e   = (const float*)d_in[8];
    const float* b_e   = (const float*)d_in[9];
    const float* W_out = (const float*)d_in[10];
    const float* b_out = (const float*)d_in[11];
    float* out = (float*)d_out;

    const long SZ = (long)B_ * N_ * 512;  // 327680
    float* ws  = (float*)d_ws;
    float* x   = ws;            // [640][512]
    float* q   = ws + SZ;       // [640][512]
    float* k_t = ws + 2 * SZ;   // [b][512][320]
    float* v   = ws + 3 * SZ;   // [640][512]
    float* t   = ws + 4 * SZ;   // [640][512] = [blk][h*64+c]
    float* o   = ws + 5 * SZ;   // [640][512]

    // x = nodes @ W_exp + b_exp
    gemm_bf16<0><<<dim3(10, 8), 256, 0, stream>>>(nodes, W_exp, b_exp, x, nullptr, 512, 512);
    // q = x @ W_q + b_q
    gemm_bf16<0><<<dim3(10, 8), 256, 0, stream>>>(x, W_q, b_q, q, nullptr, 512, 512);
    // k_t / v = x @ W_kv + b_kv (split epilogue)
    gemm_bf16<1><<<dim3(10, 16), 256, 0, stream>>>(x, W_kv, b_kv, k_t, v, 1024, 512);
    // t = per-head q @ W_e_head^T
    t_kernel<<<640, 512, 0, stream>>>(q, W_e, t);
    // fused edge-biased attention -> o
    attn_kernel<<<640, 512, 0, stream>>>(q, k_t, v, t, edges, W_e, b_e, o);
    // out = o @ W_out + b_out (f32 for final accuracy)
    gemm_f32<<<dim3(10, 8), 256, 0, stream>>>(o, W_out, b_out, out, 512, 512);
}

// Round 4
// 178.704 us; speedup vs baseline: 1.4289x; 1.4289x over previous
//
#include <hip/hip_runtime.h>

// Problem constants
#define B_  2
#define N_  320
#define H_  8
#define ED_ 64

typedef __attribute__((ext_vector_type(8))) short bf16x8;
typedef __attribute__((ext_vector_type(4))) float floatx4;

__device__ __forceinline__ ushort f2bf(float f) {
    union { float f; unsigned u; } c; c.f = f;
    unsigned u = c.u;
    return (ushort)((u + 0x7fffu + ((u >> 16) & 1u)) >> 16);
}
__device__ __forceinline__ float bf2f(ushort s) {
    union { unsigned u; float f; } c; c.u = ((unsigned)s) << 16;
    return c.f;
}
__device__ __forceinline__ uint4 packf8(const float* f) {
    uint4 r;
    r.x = (unsigned)f2bf(f[0]) | ((unsigned)f2bf(f[1]) << 16);
    r.y = (unsigned)f2bf(f[2]) | ((unsigned)f2bf(f[3]) << 16);
    r.z = (unsigned)f2bf(f[4]) | ((unsigned)f2bf(f[5]) << 16);
    r.w = (unsigned)f2bf(f[6]) | ((unsigned)f2bf(f[7]) << 16);
    return r;
}
__device__ __forceinline__ uint4 packu8(const ushort* s) {
    uint4 r;
    r.x = (unsigned)s[0] | ((unsigned)s[1] << 16);
    r.y = (unsigned)s[2] | ((unsigned)s[3] << 16);
    r.z = (unsigned)s[4] | ((unsigned)s[5] << 16);
    r.w = (unsigned)s[6] | ((unsigned)s[7] << 16);
    return r;
}

// ------------------------------------------------------------------
// prep: transpose+convert weights to bf16 [col][k] (coalesced GEMM
// staging), split W_out into hi/lo bf16, W_e -> W_eT f32, nodes -> bf16.
// blocks: 0-63 W_exp | 64-127 W_q | 128-255 W_kv | 256-319 W_out(hi/lo)
//         | 320-327 W_e^T f32 | 328-407 nodes convert
// ------------------------------------------------------------------
__global__ __launch_bounds__(256) void prep_kernel(
    const float* __restrict__ W_exp, const float* __restrict__ W_q,
    const float* __restrict__ W_kv, const float* __restrict__ W_out,
    const float* __restrict__ W_e, const float* __restrict__ nodes,
    ushort* __restrict__ WT_exp, ushort* __restrict__ WT_qkv,
    ushort* __restrict__ WT_oh, ushort* __restrict__ WT_ol,
    float* __restrict__ W_eT, ushort* __restrict__ nodes_bf)
{
    __shared__ float T[64][65];
    const int id = blockIdx.x, tid = threadIdx.x;

    if (id >= 328) {            // nodes f32 -> bf16 flat
        long base = (long)(id - 328) * 4096 + (long)tid * 16;
        float f[16];
        #pragma unroll
        for (int e = 0; e < 4; ++e) {
            float4 x4 = *(const float4*)&nodes[base + e * 4];
            f[e*4] = x4.x; f[e*4+1] = x4.y; f[e*4+2] = x4.z; f[e*4+3] = x4.w;
        }
        uint4 p0 = packf8(f), p1 = packf8(f + 8);
        *(uint4*)&nodes_bf[base] = p0;
        *(uint4*)&nodes_bf[base + 8] = p1;
        return;
    }
    if (id >= 320) {            // W_e [64][512] -> W_eT f32 [512][64]
        const int c0 = (id - 320) * 64;
        const int r = tid >> 2, cs = (tid & 3) * 16;
        #pragma unroll
        for (int e = 0; e < 4; ++e) {
            float4 x4 = *(const float4*)&W_e[(long)r * 512 + c0 + cs + e * 4];
            T[r][cs + e*4] = x4.x; T[r][cs + e*4 + 1] = x4.y;
            T[r][cs + e*4 + 2] = x4.z; T[r][cs + e*4 + 3] = x4.w;
        }
        __syncthreads();
        const int hd = c0 + (tid >> 2), ks = (tid & 3) * 16;
        #pragma unroll
        for (int e = 0; e < 4; ++e) {
            float4 o4;
            o4.x = T[ks + e*4][tid >> 2];     o4.y = T[ks + e*4 + 1][tid >> 2];
            o4.z = T[ks + e*4 + 2][tid >> 2]; o4.w = T[ks + e*4 + 3][tid >> 2];
            *(float4*)&W_eT[(long)hd * 64 + ks + e * 4] = o4;
        }
        return;
    }
    // bf16 transposes
    const float* src; ushort* dst; ushort* dstl = nullptr;
    int ldS, row0, kt, ct;
    if (id < 64)       { int l = id;       kt = l >> 3; ct = l & 7;  src = W_exp; ldS = 512;  dst = WT_exp; row0 = ct * 64; }
    else if (id < 128) { int l = id - 64;  kt = l >> 3; ct = l & 7;  src = W_q;   ldS = 512;  dst = WT_qkv; row0 = ct * 64; }
    else if (id < 256) { int l = id - 128; kt = l >> 4; ct = l & 15; src = W_kv;  ldS = 1024; dst = WT_qkv; row0 = 512 + ct * 64; }
    else               { int l = id - 256; kt = l >> 3; ct = l & 7;  src = W_out; ldS = 512;  dst = WT_oh; dstl = WT_ol; row0 = ct * 64; }
    const int k0 = kt * 64, c0 = ct * 64;
    {
        const int r = tid >> 2, cs = (tid & 3) * 16;
        #pragma unroll
        for (int e = 0; e < 4; ++e) {
            float4 x4 = *(const float4*)&src[(long)(k0 + r) * ldS + c0 + cs + e * 4];
            T[r][cs + e*4] = x4.x; T[r][cs + e*4 + 1] = x4.y;
            T[r][cs + e*4 + 2] = x4.z; T[r][cs + e*4 + 3] = x4.w;
        }
    }
    __syncthreads();
    {
        const int cc = tid >> 2, ks = (tid & 3) * 16;
        float vals[16];
        #pragma unroll
        for (int e = 0; e < 16; ++e) vals[e] = T[ks + e][cc];
        ushort* d = dst + (long)(row0 + cc) * 512 + k0 + ks;
        if (!dstl) {
            *(uint4*)d = packf8(vals);
            *(uint4*)(d + 8) = packf8(vals + 8);
        } else {
            ushort hs[16], ls[16];
            #pragma unroll
            for (int e = 0; e < 16; ++e) {
                hs[e] = f2bf(vals[e]);
                ls[e] = f2bf(vals[e] - bf2f(hs[e]));
            }
            *(uint4*)d = packu8(hs);
            *(uint4*)(d + 8) = packu8(hs + 8);
            ushort* d2 = dstl + (long)(row0 + cc) * 512 + k0 + ks;
            *(uint4*)d2 = packu8(ls);
            *(uint4*)(d2 + 8) = packu8(ls + 8);
        }
    }
}

// ------------------------------------------------------------------
// bf16 MFMA GEMM, all-coalesced staging into XOR-swizzled LDS.
// A bf16 [M][512], WT bf16 [N][512] (pre-transposed). BM=BN=64, BK=64.
// 256 thr = 4 waves (2x2), wave 32x32 = 2x2 frags, 2 k-steps.
// MODE 0: out x_bf bf16 [row][512], bias1.
// MODE 1: cn<512 q f32 (bias1) | <1024 k_t[b][hd][i] (bias2) | v (bias2).
// ------------------------------------------------------------------
template <int MODE>
__global__ __launch_bounds__(256) void gemm_v2(
    const ushort* __restrict__ A, const ushort* __restrict__ WT,
    const float* __restrict__ bias1, const float* __restrict__ bias2,
    ushort* __restrict__ outbf, float* __restrict__ q_o,
    float* __restrict__ kt_o, float* __restrict__ v_o)
{
    __shared__ ushort As[64 * 64];   // [row][k] swizzled, 8KB
    __shared__ ushort Bs[64 * 64];
    const int tid = threadIdx.x, lane = tid & 63, wid = tid >> 6;
    const int wr = wid >> 1, wc = wid & 1;
    const int bm = blockIdx.x * 64, bn = blockIdx.y * 64;
    const int srow = tid >> 2, sk = tid & 3;
    const int sw = (srow & 7) << 4;
    const int d1 = srow * 128 + ((sk * 32) ^ sw);
    const int d2 = srow * 128 + ((sk * 32 + 16) ^ sw);
    const ushort* Asrc = A + (long)(bm + srow) * 512 + sk * 16;
    const ushort* Bsrc = WT + (long)(bn + srow) * 512 + sk * 16;

    floatx4 acc[2][2] = {};
    for (int k0 = 0; k0 < 512; k0 += 64) {
        uint4 a0 = *(const uint4*)(Asrc + k0);
        uint4 a1 = *(const uint4*)(Asrc + k0 + 8);
        uint4 b0 = *(const uint4*)(Bsrc + k0);
        uint4 b1 = *(const uint4*)(Bsrc + k0 + 8);
        if (k0) __syncthreads();
        *(uint4*)((char*)As + d1) = a0;
        *(uint4*)((char*)As + d2) = a1;
        *(uint4*)((char*)Bs + d1) = b0;
        *(uint4*)((char*)Bs + d2) = b1;
        __syncthreads();
        #pragma unroll
        for (int s = 0; s < 2; ++s) {
            const int kb = s * 64 + ((lane >> 4) * 16);
            bf16x8 af[2], bfr[2];
            #pragma unroll
            for (int mf = 0; mf < 2; ++mf) {
                int row = wr * 32 + mf * 16 + (lane & 15);
                af[mf] = *(const bf16x8*)((const char*)As + row * 128 + (kb ^ ((row & 7) << 4)));
            }
            #pragma unroll
            for (int nf = 0; nf < 2; ++nf) {
                int col = wc * 32 + nf * 16 + (lane & 15);
                bfr[nf] = *(const bf16x8*)((const char*)Bs + col * 128 + (kb ^ ((col & 7) << 4)));
            }
            #pragma unroll
            for (int mf = 0; mf < 2; ++mf)
                #pragma unroll
                for (int nf = 0; nf < 2; ++nf)
                    acc[mf][nf] = __builtin_amdgcn_mfma_f32_16x16x32_bf16(
                        af[mf], bfr[nf], acc[mf][nf], 0, 0, 0);
        }
    }
    const int r4 = (lane >> 4) * 4, c16 = lane & 15;
    #pragma unroll
    for (int mf = 0; mf < 2; ++mf)
        #pragma unroll
        for (int nf = 0; nf < 2; ++nf)
            #pragma unroll
            for (int j = 0; j < 4; ++j) {
                int row = bm + wr * 32 + mf * 16 + r4 + j;
                int cn  = bn + wc * 32 + nf * 16 + c16;
                float val = acc[mf][nf][j];
                if (MODE == 0) {
                    outbf[(long)row * 512 + cn] = f2bf(val + bias1[cn]);
                } else {
                    if (cn < 512) {
                        q_o[(long)row * 512 + cn] = val + bias1[cn];
                    } else if (cn < 1024) {
                        int bb = row / N_, ii = row % N_;
                        kt_o[((long)bb * 512 + (cn - 512)) * N_ + ii] = val + bias2[cn - 512];
                    } else {
                        v_o[(long)row * 512 + (cn - 1024)] = val + bias2[cn - 512];
                    }
                }
            }
}

// ------------------------------------------------------------------
// final GEMM: out = o @ W_out + b_out at ~f32 accuracy via split-bf16:
// o = ah+al, W = bh+bl (pre-split); out ~= ah*bh + ah*bl + al*bh.
// ------------------------------------------------------------------
__global__ __launch_bounds__(256) void gemm_out(
    const float* __restrict__ Af, const ushort* __restrict__ BTh,
    const ushort* __restrict__ BTl, const float* __restrict__ bias,
    float* __restrict__ C)
{
    __shared__ ushort Ah[64 * 64], Al[64 * 64], Bh[64 * 64], Bl[64 * 64];
    const int tid = threadIdx.x, lane = tid & 63, wid = tid >> 6;
    const int wr = wid >> 1, wc = wid & 1;
    const int bm = blockIdx.x * 64, bn = blockIdx.y * 64;
    const int srow = tid >> 2, sk = tid & 3;
    const int sw = (srow & 7) << 4;
    const int d1 = srow * 128 + ((sk * 32) ^ sw);
    const int d2 = srow * 128 + ((sk * 32 + 16) ^ sw);
    const float*  asrc = Af + (long)(bm + srow) * 512 + sk * 16;
    const ushort* bhs  = BTh + (long)(bn + srow) * 512 + sk * 16;
    const ushort* bls  = BTl + (long)(bn + srow) * 512 + sk * 16;

    floatx4 acc[2][2] = {};
    for (int k0 = 0; k0 < 512; k0 += 64) {
        float f[16];
        #pragma unroll
        for (int e = 0; e < 4; ++e) {
            float4 x4 = *(const float4*)(asrc + k0 + e * 4);
            f[e*4] = x4.x; f[e*4+1] = x4.y; f[e*4+2] = x4.z; f[e*4+3] = x4.w;
        }
        ushort hs[16], ls[16];
        #pragma unroll
        for (int e = 0; e < 16; ++e) {
            hs[e] = f2bf(f[e]);
            ls[e] = f2bf(f[e] - bf2f(hs[e]));
        }
        uint4 bh0 = *(const uint4*)(bhs + k0);
        uint4 bh1 = *(const uint4*)(bhs + k0 + 8);
        uint4 bl0 = *(const uint4*)(bls + k0);
        uint4 bl1 = *(const uint4*)(bls + k0 + 8);
        if (k0) __syncthreads();
        *(uint4*)((char*)Ah + d1) = packu8(hs);
        *(uint4*)((char*)Ah + d2) = packu8(hs + 8);
        *(uint4*)((char*)Al + d1) = packu8(ls);
        *(uint4*)((char*)Al + d2) = packu8(ls + 8);
        *(uint4*)((char*)Bh + d1) = bh0;
        *(uint4*)((char*)Bh + d2) = bh1;
        *(uint4*)((char*)Bl + d1) = bl0;
        *(uint4*)((char*)Bl + d2) = bl1;
        __syncthreads();
        #pragma unroll
        for (int s = 0; s < 2; ++s) {
            const int kb = s * 64 + ((lane >> 4) * 16);
            bf16x8 ah[2], al[2], bh[2], bl[2];
            #pragma unroll
            for (int mf = 0; mf < 2; ++mf) {
                int row = wr * 32 + mf * 16 + (lane & 15);
                int off = row * 128 + (kb ^ ((row & 7) << 4));
                ah[mf] = *(const bf16x8*)((const char*)Ah + off);
                al[mf] = *(const bf16x8*)((const char*)Al + off);
            }
            #pragma unroll
            for (int nf = 0; nf < 2; ++nf) {
                int col = wc * 32 + nf * 16 + (lane & 15);
                int off = col * 128 + (kb ^ ((col & 7) << 4));
                bh[nf] = *(const bf16x8*)((const char*)Bh + off);
                bl[nf] = *(const bf16x8*)((const char*)Bl + off);
            }
            #pragma unroll
            for (int mf = 0; mf < 2; ++mf)
                #pragma unroll
                for (int nf = 0; nf < 2; ++nf) {
                    acc[mf][nf] = __builtin_amdgcn_mfma_f32_16x16x32_bf16(ah[mf], bh[nf], acc[mf][nf], 0, 0, 0);
                    acc[mf][nf] = __builtin_amdgcn_mfma_f32_16x16x32_bf16(ah[mf], bl[nf], acc[mf][nf], 0, 0, 0);
                    acc[mf][nf] = __builtin_amdgcn_mfma_f32_16x16x32_bf16(al[mf], bh[nf], acc[mf][nf], 0, 0, 0);
                }
        }
    }
    const int r4 = (lane >> 4) * 4, c16 = lane & 15;
    #pragma unroll
    for (int mf = 0; mf < 2; ++mf)
        #pragma unroll
        for (int nf = 0; nf < 2; ++nf)
            #pragma unroll
            for (int j = 0; j < 4; ++j) {
                int row = bm + wr * 32 + mf * 16 + r4 + j;
                int col = bn + wc * 32 + nf * 16 + c16;
                C[(long)row * 512 + col] = acc[mf][nf][j] + bias[col];
            }
}

// ------------------------------------------------------------------
// Fused attention per (b,i): 512 thr = 8 waves, wave w == head w.
// Includes t = q_head @ W_e_head^T (via W_eT, coalesced).
// LDS 50.7KB -> 3 blocks/CU (all 640 blocks resident).
// ------------------------------------------------------------------
__global__ __launch_bounds__(512) void attn_kernel(
    const float* __restrict__ q, const float* __restrict__ k_t,
    const float* __restrict__ v, const float* __restrict__ edges,
    const float* __restrict__ W_eT, const float* __restrict__ W_e,
    const float* __restrict__ b_e, float* __restrict__ o_out)
{
    __shared__ ushort E_s[64 * 324];   // 41.5 KB bf16
    __shared__ ushort A_bf[8 * 320];   // 5 KB bf16 attn weights
    __shared__ float  q_lds[512];
    __shared__ float  tu_lds[512];     // t (phase1), then U (phase3/4)

    const int blk = blockIdx.x;
    const int b = blk / N_, i = blk % N_;
    const int tid = threadIdx.x;
    const int w = tid >> 6, lane = tid & 63;

    q_lds[tid] = q[(long)blk * 512 + tid];
    {   // E load: edges[b][c][i][j] -> bf16 LDS
        const float* ebase = edges + (long)b * ED_ * N_ * N_ + (long)i * N_;
        for (int idx = tid; idx < 64 * 160; idx += 512) {
            int c = idx / 160, jj = (idx % 160) * 2;
            float2 e2 = *(const float2*)(ebase + (long)c * (N_ * N_) + jj);
            unsigned lo = f2bf(e2.x), hi = f2bf(e2.y);
            *(unsigned*)&E_s[c * 324 + jj] = lo | (hi << 16);
        }
    }
    __syncthreads();

    // ---- t fold: t[w][lane] = sum_d q[w,d] * W_e[lane, w*64+d] ----
    {
        float tacc = 0.f;
        const float* we = W_eT + (long)(w * 64) * 64 + lane;
        const float* ql = q_lds + w * 64;
        #pragma unroll 8
        for (int d = 0; d < 64; ++d) tacc += ql[d] * we[(long)d * 64];
        tu_lds[tid] = tacc;
    }
    __syncthreads();

    // ---- Phase 1: S (lane j, 5 j-tiles of 64) ----
    float sacc[5] = {0.f, 0.f, 0.f, 0.f, 0.f};
    {
        const float* tl = tu_lds + w * 64;
        #pragma unroll 4
        for (int c = 0; c < 64; ++c) {
            float tc = tl[c];
            const ushort* er = &E_s[c * 324 + lane];
            sacc[0] += tc * bf2f(er[0]);
            sacc[1] += tc * bf2f(er[64]);
            sacc[2] += tc * bf2f(er[128]);
            sacc[3] += tc * bf2f(er[192]);
            sacc[4] += tc * bf2f(er[256]);
        }
        const float* ql = q_lds + w * 64;
        const float* kb = k_t + ((long)b * 512 + w * 64) * N_;
        #pragma unroll 4
        for (int d = 0; d < 64; ++d) {
            float qd = ql[d];
            const float* kr = kb + (long)d * N_ + lane;
            sacc[0] += qd * kr[0];
            sacc[1] += qd * kr[64];
            sacc[2] += qd * kr[128];
            sacc[3] += qd * kr[192];
            sacc[4] += qd * kr[256];
        }
    }
    const float scale = 0.125f;
    float s0 = sacc[0] * scale, s1 = sacc[1] * scale, s2 = sacc[2] * scale,
          s3 = sacc[3] * scale, s4 = sacc[4] * scale;

    // ---- Phase 2: softmax over 320, store A as bf16 ----
    float m = fmaxf(fmaxf(fmaxf(s0, s1), fmaxf(s2, s3)), s4);
    #pragma unroll
    for (int off = 32; off >= 1; off >>= 1) m = fmaxf(m, __shfl_xor(m, off, 64));
    s0 = __expf(s0 - m); s1 = __expf(s1 - m); s2 = __expf(s2 - m);
    s3 = __expf(s3 - m); s4 = __expf(s4 - m);
    float sum = s0 + s1 + s2 + s3 + s4;
    #pragma unroll
    for (int off = 32; off >= 1; off >>= 1) sum += __shfl_xor(sum, off, 64);
    float inv = 1.f / sum;
    A_bf[w * 320 + lane]       = f2bf(s0 * inv);
    A_bf[w * 320 + 64 + lane]  = f2bf(s1 * inv);
    A_bf[w * 320 + 128 + lane] = f2bf(s2 * inv);
    A_bf[w * 320 + 192 + lane] = f2bf(s3 * inv);
    A_bf[w * 320 + 256 + lane] = f2bf(s4 * inv);
    __syncthreads();

    // ---- Phase 3: acc_v (A.v) and acc_u (A.E^T), lane = d / c ----
    float acc_v = 0.f, acc_u = 0.f;
    {
        const float*  vb = v + (long)b * N_ * 512 + w * 64 + lane;
        const ushort* Er = E_s + lane * 324;
        const ushort* Ar = A_bf + w * 320;
        #pragma unroll 4
        for (int j4 = 0; j4 < 80; ++j4) {
            uint2 aa = *(const uint2*)&Ar[j4 * 4];
            float a0 = bf2f((ushort)(aa.x & 0xffffu));
            float a1 = bf2f((ushort)(aa.x >> 16));
            float a2 = bf2f((ushort)(aa.y & 0xffffu));
            float a3 = bf2f((ushort)(aa.y >> 16));
            uint2 e2 = *(const uint2*)&Er[j4 * 4];
            float e0 = bf2f((ushort)(e2.x & 0xffffu));
            float e1 = bf2f((ushort)(e2.x >> 16));
            float e2f = bf2f((ushort)(e2.y & 0xffffu));
            float e3 = bf2f((ushort)(e2.y >> 16));
            const float* vv = vb + (long)j4 * 4 * 512;
            acc_v += a0 * vv[0] + a1 * vv[512] + a2 * vv[1024] + a3 * vv[1536];
            acc_u += a0 * e0 + a1 * e1 + a2 * e2f + a3 * e3;
        }
    }
    tu_lds[tid] = acc_u;   // t is dead; reuse as U
    __syncthreads();

    // ---- Phase 4: project U through W_e_head, add b_e, write o ----
    float o_val = acc_v + b_e[w * 64 + lane];
    {
        const float* wb = W_e + w * 64 + lane;
        const float* Ur = tu_lds + w * 64;
        #pragma unroll 8
        for (int c = 0; c < 64; ++c)
            o_val += Ur[c] * wb[(long)c * 512];
    }
    o_out[(long)blk * 512 + w * 64 + lane] = o_val;
}

// ------------------------------------------------------------------
extern "C" void kernel_launch(void* const* d_in, const int* in_sizes, int n_in,
                              void* d_out, int out_size, void* d_ws, size_t ws_size,
                              hipStream_t stream)
{
    const float* nodes = (const float*)d_in[0];
    const float* edges = (const float*)d_in[1];
    const float* W_exp = (const float*)d_in[2];
    const float* b_exp = (const float*)d_in[3];
    const float* W_q   = (const float*)d_in[4];
    const float* b_q   = (const float*)d_in[5];
    const float* W_kv  = (const float*)d_in[6];
    const float* b_kv  = (const float*)d_in[7];
    const float* W_e   = (const float*)d_in[8];
    const float* b_e   = (const float*)d_in[9];
    const float* W_out = (const float*)d_in[10];
    const float* b_out = (const float*)d_in[11];
    float* out = (float*)d_out;

    const long SZ = (long)B_ * N_ * 512;   // 327680
    float* ws  = (float*)d_ws;
    float* q   = ws;                // [640][512]
    float* k_t = ws + SZ;           // [b][512][320]
    float* v   = ws + 2 * SZ;       // [640][512]
    float* o   = ws + 3 * SZ;       // [640][512]
    ushort* x_bf     = (ushort*)(ws + 4 * SZ);   // [640][512] bf16
    ushort* nodes_bf = x_bf + SZ;                 // [640][512] bf16
    ushort* WT_exp   = nodes_bf + SZ;             // [512][512]
    ushort* WT_qkv   = WT_exp + 262144;           // [1536][512]
    ushort* WT_oh    = WT_qkv + 786432;           // [512][512]
    ushort* WT_ol    = WT_oh + 262144;            // [512][512]
    float*  W_eT     = (float*)(WT_ol + 262144);  // [512][64] f32

    // 1. prep: weight transposes/converts + nodes->bf16
    prep_kernel<<<408, 256, 0, stream>>>(W_exp, W_q, W_kv, W_out, W_e, nodes,
                                         WT_exp, WT_qkv, WT_oh, WT_ol, W_eT, nodes_bf);
    // 2. x = nodes @ W_exp + b_exp  (bf16 out)
    gemm_v2<0><<<dim3(10, 8), 256, 0, stream>>>(nodes_bf, WT_exp, b_exp, nullptr,
                                                x_bf, nullptr, nullptr, nullptr);
    // 3. q | k_t | v = x @ [W_q | W_kv] + b
    gemm_v2<1><<<dim3(10, 24), 256, 0, stream>>>(x_bf, WT_qkv, b_q, b_kv,
                                                 nullptr, q, k_t, v);
    // 4. fused attention (incl. t) -> o
    attn_kernel<<<640, 512, 0, stream>>>(q, k_t, v, edges, W_eT, W_e, b_e, o);
    // 5. out = o @ W_out + b_out (split-bf16, ~f32 accuracy)
    gemm_out<<<dim3(10, 8), 256, 0, stream>>>(o, WT_oh, WT_ol, b_out, out);
}

// Round 5
// 177.214 us; speedup vs baseline: 1.4409x; 1.0084x over previous
//
#include <hip/hip_runtime.h>

// Problem constants
#define B_  2
#define N_  320
#define H_  8
#define ED_ 64

typedef __attribute__((ext_vector_type(8))) short bf16x8;
typedef __attribute__((ext_vector_type(4))) float floatx4;

__device__ __forceinline__ ushort f2bf(float f) {
    union { float f; unsigned u; } c; c.f = f;
    unsigned u = c.u;
    return (ushort)((u + 0x7fffu + ((u >> 16) & 1u)) >> 16);
}
__device__ __forceinline__ float bf2f(ushort s) {
    union { unsigned u; float f; } c; c.u = ((unsigned)s) << 16;
    return c.f;
}
__device__ __forceinline__ uint4 packf8(const float* f) {
    uint4 r;
    r.x = (unsigned)f2bf(f[0]) | ((unsigned)f2bf(f[1]) << 16);
    r.y = (unsigned)f2bf(f[2]) | ((unsigned)f2bf(f[3]) << 16);
    r.z = (unsigned)f2bf(f[4]) | ((unsigned)f2bf(f[5]) << 16);
    r.w = (unsigned)f2bf(f[6]) | ((unsigned)f2bf(f[7]) << 16);
    return r;
}
__device__ __forceinline__ uint4 packu8(const ushort* s) {
    uint4 r;
    r.x = (unsigned)s[0] | ((unsigned)s[1] << 16);
    r.y = (unsigned)s[2] | ((unsigned)s[3] << 16);
    r.z = (unsigned)s[4] | ((unsigned)s[5] << 16);
    r.w = (unsigned)s[6] | ((unsigned)s[7] << 16);
    return r;
}

// ------------------------------------------------------------------
// prep: weight transposes to bf16 [col][k]; W_out hi/lo; W_e -> W_eT
// f32 [hd][c] + Wehi/Welo bf16 [hd][c].
// blocks: 0-63 W_exp | 64-127 W_q | 128-255 W_kv | 256-319 W_out | 320-327 W_e
// ------------------------------------------------------------------
__global__ __launch_bounds__(256) void prep_kernel(
    const float* __restrict__ W_exp, const float* __restrict__ W_q,
    const float* __restrict__ W_kv, const float* __restrict__ W_out,
    const float* __restrict__ W_e,
    ushort* __restrict__ WT_exp, ushort* __restrict__ WT_qkv,
    ushort* __restrict__ WT_oh, ushort* __restrict__ WT_ol,
    float* __restrict__ W_eT, ushort* __restrict__ Wehi, ushort* __restrict__ Welo)
{
    __shared__ float T[64][65];
    const int id = blockIdx.x, tid = threadIdx.x;

    if (id >= 320) {            // W_e [64][512] -> W_eT f32 [512][64] + hi/lo bf16
        const int c0 = (id - 320) * 64;
        const int r = tid >> 2, cs = (tid & 3) * 16;
        #pragma unroll
        for (int e = 0; e < 4; ++e) {
            float4 x4 = *(const float4*)&W_e[(long)r * 512 + c0 + cs + e * 4];
            T[r][cs + e*4] = x4.x; T[r][cs + e*4 + 1] = x4.y;
            T[r][cs + e*4 + 2] = x4.z; T[r][cs + e*4 + 3] = x4.w;
        }
        __syncthreads();
        const int cc = tid >> 2, ks = (tid & 3) * 16;
        const int hd = c0 + cc;
        float vals[16]; ushort hs[16], ls[16];
        #pragma unroll
        for (int e = 0; e < 16; ++e) {
            vals[e] = T[ks + e][cc];
            hs[e] = f2bf(vals[e]);
            ls[e] = f2bf(vals[e] - bf2f(hs[e]));
        }
        #pragma unroll
        for (int e = 0; e < 4; ++e) {
            float4 o4; o4.x = vals[e*4]; o4.y = vals[e*4+1]; o4.z = vals[e*4+2]; o4.w = vals[e*4+3];
            *(float4*)&W_eT[(long)hd * 64 + ks + e * 4] = o4;
        }
        *(uint4*)&Wehi[(long)hd * 64 + ks]     = packu8(hs);
        *(uint4*)&Wehi[(long)hd * 64 + ks + 8] = packu8(hs + 8);
        *(uint4*)&Welo[(long)hd * 64 + ks]     = packu8(ls);
        *(uint4*)&Welo[(long)hd * 64 + ks + 8] = packu8(ls + 8);
        return;
    }
    const float* src; ushort* dst; ushort* dstl = nullptr;
    int ldS, row0, kt, ct;
    if (id < 64)       { int l = id;       kt = l >> 3; ct = l & 7;  src = W_exp; ldS = 512;  dst = WT_exp; row0 = ct * 64; }
    else if (id < 128) { int l = id - 64;  kt = l >> 3; ct = l & 7;  src = W_q;   ldS = 512;  dst = WT_qkv; row0 = ct * 64; }
    else if (id < 256) { int l = id - 128; kt = l >> 4; ct = l & 15; src = W_kv;  ldS = 1024; dst = WT_qkv; row0 = 512 + ct * 64; }
    else               { int l = id - 256; kt = l >> 3; ct = l & 7;  src = W_out; ldS = 512;  dst = WT_oh; dstl = WT_ol; row0 = ct * 64; }
    const int k0 = kt * 64, c0 = ct * 64;
    {
        const int r = tid >> 2, cs = (tid & 3) * 16;
        #pragma unroll
        for (int e = 0; e < 4; ++e) {
            float4 x4 = *(const float4*)&src[(long)(k0 + r) * ldS + c0 + cs + e * 4];
            T[r][cs + e*4] = x4.x; T[r][cs + e*4 + 1] = x4.y;
            T[r][cs + e*4 + 2] = x4.z; T[r][cs + e*4 + 3] = x4.w;
        }
    }
    __syncthreads();
    {
        const int cc = tid >> 2, ks = (tid & 3) * 16;
        float vals[16];
        #pragma unroll
        for (int e = 0; e < 16; ++e) vals[e] = T[ks + e][cc];
        ushort* d = dst + (long)(row0 + cc) * 512 + k0 + ks;
        if (!dstl) {
            *(uint4*)d = packf8(vals);
            *(uint4*)(d + 8) = packf8(vals + 8);
        } else {
            ushort hs[16], ls[16];
            #pragma unroll
            for (int e = 0; e < 16; ++e) {
                hs[e] = f2bf(vals[e]);
                ls[e] = f2bf(vals[e] - bf2f(hs[e]));
            }
            *(uint4*)d = packu8(hs);
            *(uint4*)(d + 8) = packu8(hs + 8);
            ushort* d2 = dstl + (long)(row0 + cc) * 512 + k0 + ks;
            *(uint4*)d2 = packu8(ls);
            *(uint4*)(d2 + 8) = packu8(ls + 8);
        }
    }
}

// ------------------------------------------------------------------
// bf16 MFMA GEMM. MODE 0: A=nodes f32, out x_bf bf16 (bias1).
// MODE 1: A=x_bf, cols: [0,512) q f32 | [512,1024) k f32 | [1024,1536)
//         v -> LDS-transposed to v_t[b][hd][i] f32 (bias2 for k,v).
// ------------------------------------------------------------------
template <int MODE>
__global__ __launch_bounds__(256) void gemm_v2(
    const void* __restrict__ Asrc, const ushort* __restrict__ WT,
    const float* __restrict__ bias1, const float* __restrict__ bias2,
    ushort* __restrict__ outbf, float* __restrict__ q_o,
    float* __restrict__ k_o, float* __restrict__ vt_o)
{
    __shared__ ushort As[64 * 64];
    __shared__ ushort Bs[64 * 64];
    __shared__ float  T[64][65];
    const int tid = threadIdx.x, lane = tid & 63, wid = tid >> 6;
    const int wr = wid >> 1, wc = wid & 1;
    const int bm = blockIdx.x * 64, bn = blockIdx.y * 64;
    const int srow = tid >> 2, sk = tid & 3;
    const int sw = (srow & 7) << 4;
    const int d1 = srow * 128 + ((sk * 32) ^ sw);
    const int d2 = srow * 128 + ((sk * 32 + 16) ^ sw);
    const ushort* Bsrc = WT + (long)(bn + srow) * 512 + sk * 16;

    floatx4 acc[2][2] = {};
    for (int k0 = 0; k0 < 512; k0 += 64) {
        uint4 a0, a1;
        if (MODE == 0) {
            const float* ap = (const float*)Asrc + (long)(bm + srow) * 512 + k0 + sk * 16;
            float f[16];
            #pragma unroll
            for (int e = 0; e < 4; ++e) {
                float4 x4 = *(const float4*)(ap + e * 4);
                f[e*4] = x4.x; f[e*4+1] = x4.y; f[e*4+2] = x4.z; f[e*4+3] = x4.w;
            }
            a0 = packf8(f); a1 = packf8(f + 8);
        } else {
            const ushort* ap = (const ushort*)Asrc + (long)(bm + srow) * 512 + k0 + sk * 16;
            a0 = *(const uint4*)ap; a1 = *(const uint4*)(ap + 8);
        }
        uint4 b0 = *(const uint4*)(Bsrc + k0);
        uint4 b1 = *(const uint4*)(Bsrc + k0 + 8);
        if (k0) __syncthreads();
        *(uint4*)((char*)As + d1) = a0;
        *(uint4*)((char*)As + d2) = a1;
        *(uint4*)((char*)Bs + d1) = b0;
        *(uint4*)((char*)Bs + d2) = b1;
        __syncthreads();
        #pragma unroll
        for (int s = 0; s < 2; ++s) {
            const int kb = s * 64 + ((lane >> 4) * 16);
            bf16x8 af[2], bfr[2];
            #pragma unroll
            for (int mf = 0; mf < 2; ++mf) {
                int row = wr * 32 + mf * 16 + (lane & 15);
                af[mf] = *(const bf16x8*)((const char*)As + row * 128 + (kb ^ ((row & 7) << 4)));
            }
            #pragma unroll
            for (int nf = 0; nf < 2; ++nf) {
                int col = wc * 32 + nf * 16 + (lane & 15);
                bfr[nf] = *(const bf16x8*)((const char*)Bs + col * 128 + (kb ^ ((col & 7) << 4)));
            }
            #pragma unroll
            for (int mf = 0; mf < 2; ++mf)
                #pragma unroll
                for (int nf = 0; nf < 2; ++nf)
                    acc[mf][nf] = __builtin_amdgcn_mfma_f32_16x16x32_bf16(
                        af[mf], bfr[nf], acc[mf][nf], 0, 0, 0);
        }
    }
    const int r4 = (lane >> 4) * 4, c16 = lane & 15;
    if (MODE == 0) {
        #pragma unroll
        for (int mf = 0; mf < 2; ++mf)
            #pragma unroll
            for (int nf = 0; nf < 2; ++nf)
                #pragma unroll
                for (int j = 0; j < 4; ++j) {
                    int row = bm + wr * 32 + mf * 16 + r4 + j;
                    int cn  = bn + wc * 32 + nf * 16 + c16;
                    outbf[(long)row * 512 + cn] = f2bf(acc[mf][nf][j] + bias1[cn]);
                }
    } else {
        const int cat = blockIdx.y >> 3;
        if (cat == 0) {
            #pragma unroll
            for (int mf = 0; mf < 2; ++mf)
                #pragma unroll
                for (int nf = 0; nf < 2; ++nf)
                    #pragma unroll
                    for (int j = 0; j < 4; ++j) {
                        int row = bm + wr * 32 + mf * 16 + r4 + j;
                        int cn  = bn + wc * 32 + nf * 16 + c16;
                        q_o[(long)row * 512 + cn] = acc[mf][nf][j] + bias1[cn];
                    }
        } else if (cat == 1) {
            #pragma unroll
            for (int mf = 0; mf < 2; ++mf)
                #pragma unroll
                for (int nf = 0; nf < 2; ++nf)
                    #pragma unroll
                    for (int j = 0; j < 4; ++j) {
                        int row = bm + wr * 32 + mf * 16 + r4 + j;
                        int cn  = bn + wc * 32 + nf * 16 + c16;
                        k_o[(long)row * 512 + (cn - 512)] = acc[mf][nf][j] + bias2[cn - 512];
                    }
        } else {
            // v: transpose via LDS -> v_t[b][hd][i]
            #pragma unroll
            for (int mf = 0; mf < 2; ++mf)
                #pragma unroll
                for (int nf = 0; nf < 2; ++nf)
                    #pragma unroll
                    for (int j = 0; j < 4; ++j) {
                        int rl = wr * 32 + mf * 16 + r4 + j;
                        int cl = wc * 32 + nf * 16 + c16;
                        T[rl][cl] = acc[mf][nf][j] + bias2[bn - 512 + cl];
                    }
            __syncthreads();
            const int cl = tid >> 2, rl4 = (tid & 3) * 16;
            const int bb = bm / N_, ii0 = bm % N_, cv0 = bn - 1024;
            const long orow = (long)bb * 512 + cv0 + cl;
            #pragma unroll
            for (int e4 = 0; e4 < 4; ++e4) {
                float4 o4;
                o4.x = T[rl4 + e4*4 + 0][cl]; o4.y = T[rl4 + e4*4 + 1][cl];
                o4.z = T[rl4 + e4*4 + 2][cl]; o4.w = T[rl4 + e4*4 + 3][cl];
                *(float4*)&vt_o[orow * N_ + ii0 + rl4 + e4*4] = o4;
            }
        }
    }
}

// ------------------------------------------------------------------
// K_qk: S[b,h,i,j] = scale * q_head @ k_head^T, q split hi/lo for
// near-f32 accuracy. Grid (5 i-tiles, 16 bh), 256 thr.
// ------------------------------------------------------------------
__global__ __launch_bounds__(256) void k_qk(
    const float* __restrict__ q, const float* __restrict__ k,
    float* __restrict__ S_g)
{
    __shared__ ushort Qh[64 * 64], Ql[64 * 64], Kt[320 * 64];
    const int it = blockIdx.x, bh = blockIdx.y;
    const int b = bh >> 3, h = bh & 7;
    const int tid = threadIdx.x, lane = tid & 63, wid = tid >> 6;
    const int srow = tid >> 2, sk = tid & 3;
    const int sw = (srow & 7) << 4;
    const int d1 = srow * 128 + ((sk * 32) ^ sw);
    const int d2 = srow * 128 + ((sk * 32 + 16) ^ sw);

    {   // Q tile (scaled by 0.125, hi/lo split)
        const float* ap = q + (long)(b * N_ + it * 64 + srow) * 512 + h * 64 + sk * 16;
        float f[16]; ushort hs[16], ls[16];
        #pragma unroll
        for (int e = 0; e < 4; ++e) {
            float4 x4 = *(const float4*)(ap + e * 4);
            f[e*4] = 0.125f * x4.x; f[e*4+1] = 0.125f * x4.y;
            f[e*4+2] = 0.125f * x4.z; f[e*4+3] = 0.125f * x4.w;
        }
        #pragma unroll
        for (int e = 0; e < 16; ++e) {
            hs[e] = f2bf(f[e]);
            ls[e] = f2bf(f[e] - bf2f(hs[e]));
        }
        *(uint4*)((char*)Qh + d1) = packu8(hs);
        *(uint4*)((char*)Qh + d2) = packu8(hs + 8);
        *(uint4*)((char*)Ql + d1) = packu8(ls);
        *(uint4*)((char*)Ql + d2) = packu8(ls + 8);
    }
    #pragma unroll
    for (int p = 0; p < 5; ++p) {   // K tiles: 320 rows
        const int row = p * 64 + srow;
        const float* kp = k + (long)(b * N_ + row) * 512 + h * 64 + sk * 16;
        float f[16];
        #pragma unroll
        for (int e = 0; e < 4; ++e) {
            float4 x4 = *(const float4*)(kp + e * 4);
            f[e*4] = x4.x; f[e*4+1] = x4.y; f[e*4+2] = x4.z; f[e*4+3] = x4.w;
        }
        *(uint4*)((char*)Kt + row * 128 + ((sk * 32) ^ sw))      = packf8(f);
        *(uint4*)((char*)Kt + row * 128 + ((sk * 32 + 16) ^ sw)) = packf8(f + 8);
    }
    __syncthreads();

    const int j0w = wid * 80;
    floatx4 acc[4][5] = {};
    #pragma unroll
    for (int s = 0; s < 2; ++s) {
        const int kb = s * 64 + ((lane >> 4) * 16);
        bf16x8 afh[4], afl[4], bf[5];
        #pragma unroll
        for (int mf = 0; mf < 4; ++mf) {
            int row = mf * 16 + (lane & 15);
            int off = row * 128 + (kb ^ ((row & 7) << 4));
            afh[mf] = *(const bf16x8*)((const char*)Qh + off);
            afl[mf] = *(const bf16x8*)((const char*)Ql + off);
        }
        #pragma unroll
        for (int jt = 0; jt < 5; ++jt) {
            int row = j0w + jt * 16 + (lane & 15);
            bf[jt] = *(const bf16x8*)((const char*)Kt + row * 128 + (kb ^ ((row & 7) << 4)));
        }
        #pragma unroll
        for (int mf = 0; mf < 4; ++mf)
            #pragma unroll
            for (int jt = 0; jt < 5; ++jt) {
                acc[mf][jt] = __builtin_amdgcn_mfma_f32_16x16x32_bf16(afh[mf], bf[jt], acc[mf][jt], 0, 0, 0);
                acc[mf][jt] = __builtin_amdgcn_mfma_f32_16x16x32_bf16(afl[mf], bf[jt], acc[mf][jt], 0, 0, 0);
            }
    }
    const int r4 = (lane >> 4) * 4, c16 = lane & 15;
    #pragma unroll
    for (int mf = 0; mf < 4; ++mf)
        #pragma unroll
        for (int jt = 0; jt < 5; ++jt)
            #pragma unroll
            for (int e = 0; e < 4; ++e) {
                int ri = it * 64 + mf * 16 + r4 + e;
                int cj = j0w + jt * 16 + c16;
                S_g[((long)bh * N_ + ri) * N_ + cj] = acc[mf][jt][e];
            }
}

// ------------------------------------------------------------------
// attn v3 per (b,i): stage E bf16, t = q@W_e_head^T, S_e = t.E (VALU),
// S = S_e*scale + S_qk, softmax -> A (bf16, LDS+global), U = A.E^T.
// LDS 50.7 KB -> 3 blocks/CU.
// ------------------------------------------------------------------
__global__ __launch_bounds__(512) void attn_kernel(
    const float* __restrict__ q, const float* __restrict__ S_g,
    const float* __restrict__ edges, const float* __restrict__ W_eT,
    ushort* __restrict__ A_g, float* __restrict__ U_g)
{
    __shared__ ushort E_s[64 * 324];   // 41.5 KB
    __shared__ ushort A_lds[8 * 320];  // 5 KB
    __shared__ float  q_lds[512];
    __shared__ float  t_lds[512];

    const int blk = blockIdx.x;
    const int b = blk / N_, i = blk % N_;
    const int tid = threadIdx.x;
    const int w = tid >> 6, lane = tid & 63;

    q_lds[tid] = q[(long)blk * 512 + tid];
    {   // E stage: float4 reads
        const float* ebase = edges + (long)b * ED_ * N_ * N_ + (long)i * N_;
        for (int idx = tid; idx < 64 * 80; idx += 512) {
            int c = idx / 80, j4 = (idx % 80) * 4;
            float4 e4 = *(const float4*)(ebase + (long)c * (N_ * N_) + j4);
            uint2 pk;
            pk.x = (unsigned)f2bf(e4.x) | ((unsigned)f2bf(e4.y) << 16);
            pk.y = (unsigned)f2bf(e4.z) | ((unsigned)f2bf(e4.w) << 16);
            *(uint2*)&E_s[c * 324 + j4] = pk;
        }
    }
    __syncthreads();

    // t[w][lane] = sum_d q[w,d] * W_eT[w*64+d][lane]
    {
        float tacc = 0.f;
        const float* we = W_eT + (long)(w * 64) * 64 + lane;
        const float* ql = q_lds + w * 64;
        #pragma unroll 8
        for (int d = 0; d < 64; ++d) tacc += ql[d] * we[(long)d * 64];
        t_lds[tid] = tacc;
    }
    __syncthreads();

    // S_e (VALU) + S_qk (precomputed)
    float sacc[5] = {0.f, 0.f, 0.f, 0.f, 0.f};
    {
        const float* tl = t_lds + w * 64;
        #pragma unroll 4
        for (int c = 0; c < 64; ++c) {
            float tc = tl[c];
            const ushort* er = &E_s[c * 324 + lane];
            sacc[0] += tc * bf2f(er[0]);
            sacc[1] += tc * bf2f(er[64]);
            sacc[2] += tc * bf2f(er[128]);
            sacc[3] += tc * bf2f(er[192]);
            sacc[4] += tc * bf2f(er[256]);
        }
    }
    const long sbase = ((long)(b * 8 + w) * N_ + i) * N_ + lane;
    const float scale = 0.125f;
    float s0 = sacc[0] * scale + S_g[sbase];
    float s1 = sacc[1] * scale + S_g[sbase + 64];
    float s2 = sacc[2] * scale + S_g[sbase + 128];
    float s3 = sacc[3] * scale + S_g[sbase + 192];
    float s4 = sacc[4] * scale + S_g[sbase + 256];

    // softmax over 320
    float m = fmaxf(fmaxf(fmaxf(s0, s1), fmaxf(s2, s3)), s4);
    #pragma unroll
    for (int off = 32; off >= 1; off >>= 1) m = fmaxf(m, __shfl_xor(m, off, 64));
    s0 = __expf(s0 - m); s1 = __expf(s1 - m); s2 = __expf(s2 - m);
    s3 = __expf(s3 - m); s4 = __expf(s4 - m);
    float sum = s0 + s1 + s2 + s3 + s4;
    #pragma unroll
    for (int off = 32; off >= 1; off >>= 1) sum += __shfl_xor(sum, off, 64);
    float inv = 1.f / sum;
    ushort a0 = f2bf(s0 * inv), a1 = f2bf(s1 * inv), a2 = f2bf(s2 * inv),
           a3 = f2bf(s3 * inv), a4 = f2bf(s4 * inv);
    A_lds[w * 320 + lane]       = a0;
    A_lds[w * 320 + 64 + lane]  = a1;
    A_lds[w * 320 + 128 + lane] = a2;
    A_lds[w * 320 + 192 + lane] = a3;
    A_lds[w * 320 + 256 + lane] = a4;
    A_g[sbase]       = a0;
    A_g[sbase + 64]  = a1;
    A_g[sbase + 128] = a2;
    A_g[sbase + 192] = a3;
    A_g[sbase + 256] = a4;
    __syncthreads();

    // U[w][lane=c] = sum_j A[w][j] * E[c][j]
    float acc_u = 0.f;
    {
        const ushort* Er = E_s + lane * 324;
        const ushort* Ar = A_lds + w * 320;
        #pragma unroll 4
        for (int j4 = 0; j4 < 80; ++j4) {
            uint2 aa = *(const uint2*)&Ar[j4 * 4];
            uint2 e2 = *(const uint2*)&Er[j4 * 4];
            acc_u += bf2f((ushort)(aa.x & 0xffffu)) * bf2f((ushort)(e2.x & 0xffffu));
            acc_u += bf2f((ushort)(aa.x >> 16))     * bf2f((ushort)(e2.x >> 16));
            acc_u += bf2f((ushort)(aa.y & 0xffffu)) * bf2f((ushort)(e2.y & 0xffffu));
            acc_u += bf2f((ushort)(aa.y >> 16))     * bf2f((ushort)(e2.y >> 16));
        }
    }
    U_g[((long)(b * 8 + w) * N_ + i) * 64 + lane] = acc_u;
}

// ------------------------------------------------------------------
// K_Ov: O = A@v_head + U@W_e_head + b_e, per (b,h) i-tile. v and the
// U/W_e product are hi/lo split for accuracy. Grid (5, 16), 256 thr.
// ------------------------------------------------------------------
__global__ __launch_bounds__(256) void k_ov(
    const ushort* __restrict__ A_g, const float* __restrict__ vt,
    const float* __restrict__ U_g, const ushort* __restrict__ Wh_g,
    const ushort* __restrict__ Wl_g, const float* __restrict__ b_e,
    float* __restrict__ o_out)
{
    __shared__ ushort B0[64 * 64], B1[64 * 64], B2[64 * 64], B3[64 * 64];
    const int it = blockIdx.x, bh = blockIdx.y;
    const int b = bh >> 3, h = bh & 7;
    const int tid = threadIdx.x, lane = tid & 63, wid = tid >> 6;
    const int wr = wid >> 1, wc = wid & 1;
    const int srow = tid >> 2, sk = tid & 3;
    const int sw = (srow & 7) << 4;
    const int d1 = srow * 128 + ((sk * 32) ^ sw);
    const int d2 = srow * 128 + ((sk * 32 + 16) ^ sw);

    floatx4 acc[2][2] = {};
    for (int j0 = 0; j0 < 320; j0 += 64) {
        const ushort* ap = A_g + ((long)bh * N_ + it * 64 + srow) * N_ + j0 + sk * 16;
        uint4 a0 = *(const uint4*)ap, a1 = *(const uint4*)(ap + 8);
        const float* vp = vt + ((long)b * 512 + h * 64 + srow) * N_ + j0 + sk * 16;
        float f[16]; ushort hs[16], ls[16];
        #pragma unroll
        for (int e = 0; e < 4; ++e) {
            float4 x4 = *(const float4*)(vp + e * 4);
            f[e*4] = x4.x; f[e*4+1] = x4.y; f[e*4+2] = x4.z; f[e*4+3] = x4.w;
        }
        #pragma unroll
        for (int e = 0; e < 16; ++e) {
            hs[e] = f2bf(f[e]);
            ls[e] = f2bf(f[e] - bf2f(hs[e]));
        }
        if (j0) __syncthreads();
        *(uint4*)((char*)B0 + d1) = a0;
        *(uint4*)((char*)B0 + d2) = a1;
        *(uint4*)((char*)B1 + d1) = packu8(hs);
        *(uint4*)((char*)B1 + d2) = packu8(hs + 8);
        *(uint4*)((char*)B2 + d1) = packu8(ls);
        *(uint4*)((char*)B2 + d2) = packu8(ls + 8);
        __syncthreads();
        #pragma unroll
        for (int s = 0; s < 2; ++s) {
            const int kb = s * 64 + ((lane >> 4) * 16);
            bf16x8 af[2], bh_[2], bl_[2];
            #pragma unroll
            for (int mf = 0; mf < 2; ++mf) {
                int row = wr * 32 + mf * 16 + (lane & 15);
                af[mf] = *(const bf16x8*)((const char*)B0 + row * 128 + (kb ^ ((row & 7) << 4)));
            }
            #pragma unroll
            for (int nf = 0; nf < 2; ++nf) {
                int col = wc * 32 + nf * 16 + (lane & 15);
                int off = col * 128 + (kb ^ ((col & 7) << 4));
                bh_[nf] = *(const bf16x8*)((const char*)B1 + off);
                bl_[nf] = *(const bf16x8*)((const char*)B2 + off);
            }
            #pragma unroll
            for (int mf = 0; mf < 2; ++mf)
                #pragma unroll
                for (int nf = 0; nf < 2; ++nf) {
                    acc[mf][nf] = __builtin_amdgcn_mfma_f32_16x16x32_bf16(af[mf], bh_[nf], acc[mf][nf], 0, 0, 0);
                    acc[mf][nf] = __builtin_amdgcn_mfma_f32_16x16x32_bf16(af[mf], bl_[nf], acc[mf][nf], 0, 0, 0);
                }
        }
    }
    // U @ W_e_head (hi/lo both operands, 3 products)
    {
        const float* up = U_g + ((long)bh * N_ + it * 64 + srow) * 64 + sk * 16;
        float f[16]; ushort uh[16], ul[16];
        #pragma unroll
        for (int e = 0; e < 4; ++e) {
            float4 x4 = *(const float4*)(up + e * 4);
            f[e*4] = x4.x; f[e*4+1] = x4.y; f[e*4+2] = x4.z; f[e*4+3] = x4.w;
        }
        #pragma unroll
        for (int e = 0; e < 16; ++e) {
            uh[e] = f2bf(f[e]);
            ul[e] = f2bf(f[e] - bf2f(uh[e]));
        }
        const ushort* whp = Wh_g + ((long)h * 64 + srow) * 64 + sk * 16;
        const ushort* wlp = Wl_g + ((long)h * 64 + srow) * 64 + sk * 16;
        uint4 w0 = *(const uint4*)whp, w1 = *(const uint4*)(whp + 8);
        uint4 x0 = *(const uint4*)wlp, x1 = *(const uint4*)(wlp + 8);
        __syncthreads();
        *(uint4*)((char*)B0 + d1) = packu8(uh);
        *(uint4*)((char*)B0 + d2) = packu8(uh + 8);
        *(uint4*)((char*)B1 + d1) = packu8(ul);
        *(uint4*)((char*)B1 + d2) = packu8(ul + 8);
        *(uint4*)((char*)B2 + d1) = w0;
        *(uint4*)((char*)B2 + d2) = w1;
        *(uint4*)((char*)B3 + d1) = x0;
        *(uint4*)((char*)B3 + d2) = x1;
        __syncthreads();
        #pragma unroll
        for (int s = 0; s < 2; ++s) {
            const int kb = s * 64 + ((lane >> 4) * 16);
            bf16x8 ah[2], al[2], wh_[2], wl_[2];
            #pragma unroll
            for (int mf = 0; mf < 2; ++mf) {
                int row = wr * 32 + mf * 16 + (lane & 15);
                int off = row * 128 + (kb ^ ((row & 7) << 4));
                ah[mf] = *(const bf16x8*)((const char*)B0 + off);
                al[mf] = *(const bf16x8*)((const char*)B1 + off);
            }
            #pragma unroll
            for (int nf = 0; nf < 2; ++nf) {
                int col = wc * 32 + nf * 16 + (lane & 15);
                int off = col * 128 + (kb ^ ((col & 7) << 4));
                wh_[nf] = *(const bf16x8*)((const char*)B2 + off);
                wl_[nf] = *(const bf16x8*)((const char*)B3 + off);
            }
            #pragma unroll
            for (int mf = 0; mf < 2; ++mf)
                #pragma unroll
                for (int nf = 0; nf < 2; ++nf) {
                    acc[mf][nf] = __builtin_amdgcn_mfma_f32_16x16x32_bf16(ah[mf], wh_[nf], acc[mf][nf], 0, 0, 0);
                    acc[mf][nf] = __builtin_amdgcn_mfma_f32_16x16x32_bf16(al[mf], wh_[nf], acc[mf][nf], 0, 0, 0);
                    acc[mf][nf] = __builtin_amdgcn_mfma_f32_16x16x32_bf16(ah[mf], wl_[nf], acc[mf][nf], 0, 0, 0);
                }
        }
    }
    const int r4 = (lane >> 4) * 4, c16 = lane & 15;
    #pragma unroll
    for (int mf = 0; mf < 2; ++mf)
        #pragma unroll
        for (int nf = 0; nf < 2; ++nf)
            #pragma unroll
            for (int e = 0; e < 4; ++e) {
                int row = it * 64 + wr * 32 + mf * 16 + r4 + e;
                int col = wc * 32 + nf * 16 + c16;
                o_out[((long)(b * N_ + row)) * 512 + h * 64 + col] =
                    acc[mf][nf][e] + b_e[h * 64 + col];
            }
}

// ------------------------------------------------------------------
// final GEMM: out = o @ W_out + b_out, split-bf16 (~f32 accuracy).
// ------------------------------------------------------------------
__global__ __launch_bounds__(256) void gemm_out(
    const float* __restrict__ Af, const ushort* __restrict__ BTh,
    const ushort* __restrict__ BTl, const float* __restrict__ bias,
    float* __restrict__ C)
{
    __shared__ ushort Ah[64 * 64], Al[64 * 64], Bh[64 * 64], Bl[64 * 64];
    const int tid = threadIdx.x, lane = tid & 63, wid = tid >> 6;
    const int wr = wid >> 1, wc = wid & 1;
    const int bm = blockIdx.x * 64, bn = blockIdx.y * 64;
    const int srow = tid >> 2, sk = tid & 3;
    const int sw = (srow & 7) << 4;
    const int d1 = srow * 128 + ((sk * 32) ^ sw);
    const int d2 = srow * 128 + ((sk * 32 + 16) ^ sw);
    const float*  asrc = Af + (long)(bm + srow) * 512 + sk * 16;
    const ushort* bhs  = BTh + (long)(bn + srow) * 512 + sk * 16;
    const ushort* bls  = BTl + (long)(bn + srow) * 512 + sk * 16;

    floatx4 acc[2][2] = {};
    for (int k0 = 0; k0 < 512; k0 += 64) {
        float f[16];
        #pragma unroll
        for (int e = 0; e < 4; ++e) {
            float4 x4 = *(const float4*)(asrc + k0 + e * 4);
            f[e*4] = x4.x; f[e*4+1] = x4.y; f[e*4+2] = x4.z; f[e*4+3] = x4.w;
        }
        ushort hs[16], ls[16];
        #pragma unroll
        for (int e = 0; e < 16; ++e) {
            hs[e] = f2bf(f[e]);
            ls[e] = f2bf(f[e] - bf2f(hs[e]));
        }
        uint4 bh0 = *(const uint4*)(bhs + k0);
        uint4 bh1 = *(const uint4*)(bhs + k0 + 8);
        uint4 bl0 = *(const uint4*)(bls + k0);
        uint4 bl1 = *(const uint4*)(bls + k0 + 8);
        if (k0) __syncthreads();
        *(uint4*)((char*)Ah + d1) = packu8(hs);
        *(uint4*)((char*)Ah + d2) = packu8(hs + 8);
        *(uint4*)((char*)Al + d1) = packu8(ls);
        *(uint4*)((char*)Al + d2) = packu8(ls + 8);
        *(uint4*)((char*)Bh + d1) = bh0;
        *(uint4*)((char*)Bh + d2) = bh1;
        *(uint4*)((char*)Bl + d1) = bl0;
        *(uint4*)((char*)Bl + d2) = bl1;
        __syncthreads();
        #pragma unroll
        for (int s = 0; s < 2; ++s) {
            const int kb = s * 64 + ((lane >> 4) * 16);
            bf16x8 ah[2], al[2], bh[2], bl[2];
            #pragma unroll
            for (int mf = 0; mf < 2; ++mf) {
                int row = wr * 32 + mf * 16 + (lane & 15);
                int off = row * 128 + (kb ^ ((row & 7) << 4));
                ah[mf] = *(const bf16x8*)((const char*)Ah + off);
                al[mf] = *(const bf16x8*)((const char*)Al + off);
            }
            #pragma unroll
            for (int nf = 0; nf < 2; ++nf) {
                int col = wc * 32 + nf * 16 + (lane & 15);
                int off = col * 128 + (kb ^ ((col & 7) << 4));
                bh[nf] = *(const bf16x8*)((const char*)Bh + off);
                bl[nf] = *(const bf16x8*)((const char*)Bl + off);
            }
            #pragma unroll
            for (int mf = 0; mf < 2; ++mf)
                #pragma unroll
                for (int nf = 0; nf < 2; ++nf) {
                    acc[mf][nf] = __builtin_amdgcn_mfma_f32_16x16x32_bf16(ah[mf], bh[nf], acc[mf][nf], 0, 0, 0);
                    acc[mf][nf] = __builtin_amdgcn_mfma_f32_16x16x32_bf16(ah[mf], bl[nf], acc[mf][nf], 0, 0, 0);
                    acc[mf][nf] = __builtin_amdgcn_mfma_f32_16x16x32_bf16(al[mf], bh[nf], acc[mf][nf], 0, 0, 0);
                }
        }
    }
    const int r4 = (lane >> 4) * 4, c16 = lane & 15;
    #pragma unroll
    for (int mf = 0; mf < 2; ++mf)
        #pragma unroll
        for (int nf = 0; nf < 2; ++nf)
            #pragma unroll
            for (int j = 0; j < 4; ++j) {
                int row = bm + wr * 32 + mf * 16 + r4 + j;
                int col = bn + wc * 32 + nf * 16 + c16;
                C[(long)row * 512 + col] = acc[mf][nf][j] + bias[col];
            }
}

// ------------------------------------------------------------------
extern "C" void kernel_launch(void* const* d_in, const int* in_sizes, int n_in,
                              void* d_out, int out_size, void* d_ws, size_t ws_size,
                              hipStream_t stream)
{
    const float* nodes = (const float*)d_in[0];
    const float* edges = (const float*)d_in[1];
    const float* W_exp = (const float*)d_in[2];
    const float* b_exp = (const float*)d_in[3];
    const float* W_q   = (const float*)d_in[4];
    const float* b_q   = (const float*)d_in[5];
    const float* W_kv  = (const float*)d_in[6];
    const float* b_kv  = (const float*)d_in[7];
    const float* W_e   = (const float*)d_in[8];
    const float* b_e   = (const float*)d_in[9];
    const float* W_out = (const float*)d_in[10];
    const float* b_out = (const float*)d_in[11];
    float* out = (float*)d_out;

    const long SZ = (long)B_ * N_ * 512;   // 327680
    float* ws   = (float*)d_ws;
    float* q    = ws;                       // [640][512]
    float* k    = ws + SZ;                  // [640][512]
    float* v_t  = ws + 2 * SZ;              // [2][512][320]
    float* U_g  = ws + 3 * SZ;              // [2][8][320][64]  (131072)
    float* S    = ws + 3 * SZ + 131072;     // [2][8][320][320] (1638400)
    float* o    = S;                        // alias: S dead after attn
    ushort* A_g    = (ushort*)(S + 1638400);        // [2][8][320][320] bf16
    ushort* x_bf   = A_g + 1638400;                 // [640][512] bf16
    ushort* WT_exp = x_bf + SZ;                     // [512][512]
    ushort* WT_qkv = WT_exp + 262144;               // [1536][512]
    ushort* WT_oh  = WT_qkv + 786432;               // [512][512]
    ushort* WT_ol  = WT_oh + 262144;                // [512][512]
    float*  W_eT   = (float*)(WT_ol + 262144);      // [512][64] f32
    ushort* Wehi   = (ushort*)(W_eT + 32768);       // [512][64] bf16
    ushort* Welo   = Wehi + 32768;                  // [512][64] bf16

    // 1. weight prep
    prep_kernel<<<328, 256, 0, stream>>>(W_exp, W_q, W_kv, W_out, W_e,
                                         WT_exp, WT_qkv, WT_oh, WT_ol,
                                         W_eT, Wehi, Welo);
    // 2. x = nodes @ W_exp + b_exp (bf16)
    gemm_v2<0><<<dim3(10, 8), 256, 0, stream>>>(nodes, WT_exp, b_exp, nullptr,
                                                x_bf, nullptr, nullptr, nullptr);
    // 3. q | k | v_t = x @ [W_q | W_kv] + b
    gemm_v2<1><<<dim3(10, 24), 256, 0, stream>>>(x_bf, WT_qkv, b_q, b_kv,
                                                 nullptr, q, k, v_t);
    // 4. S = scale * q @ k^T (per b,h)
    k_qk<<<dim3(5, 16), 256, 0, stream>>>(q, k, S);
    // 5. fused edge softmax: A, U
    attn_kernel<<<640, 512, 0, stream>>>(q, S, edges, W_eT, A_g, U_g);
    // 6. O = A@v + U@W_e + b_e
    k_ov<<<dim3(5, 16), 256, 0, stream>>>(A_g, v_t, U_g, Wehi, Welo, b_e, o);
    // 7. out = o @ W_out + b_out
    gemm_out<<<dim3(10, 8), 256, 0, stream>>>(o, WT_oh, WT_ol, b_out, out);
}

// Round 6
// 162.603 us; speedup vs baseline: 1.5704x; 1.0899x over previous
//
#include <hip/hip_runtime.h>

// Problem constants
#define B_  2
#define N_  320
#define H_  8
#define ED_ 64

typedef __attribute__((ext_vector_type(8))) short bf16x8;
typedef __attribute__((ext_vector_type(4))) float floatx4;

__device__ __forceinline__ ushort f2bf(float f) {
    union { float f; unsigned u; } c; c.f = f;
    unsigned u = c.u;
    return (ushort)((u + 0x7fffu + ((u >> 16) & 1u)) >> 16);
}
__device__ __forceinline__ float bf2f(ushort s) {
    union { unsigned u; float f; } c; c.u = ((unsigned)s) << 16;
    return c.f;
}
__device__ __forceinline__ uint4 packf8(const float* f) {
    uint4 r;
    r.x = (unsigned)f2bf(f[0]) | ((unsigned)f2bf(f[1]) << 16);
    r.y = (unsigned)f2bf(f[2]) | ((unsigned)f2bf(f[3]) << 16);
    r.z = (unsigned)f2bf(f[4]) | ((unsigned)f2bf(f[5]) << 16);
    r.w = (unsigned)f2bf(f[6]) | ((unsigned)f2bf(f[7]) << 16);
    return r;
}
__device__ __forceinline__ uint4 packu8(const ushort* s) {
    uint4 r;
    r.x = (unsigned)s[0] | ((unsigned)s[1] << 16);
    r.y = (unsigned)s[2] | ((unsigned)s[3] << 16);
    r.z = (unsigned)s[4] | ((unsigned)s[5] << 16);
    r.w = (unsigned)s[6] | ((unsigned)s[7] << 16);
    return r;
}
__device__ __forceinline__ bf16x8 u4bf(uint4 u) {
    union { uint4 u; bf16x8 b; } c; c.u = u; return c.b;
}

// ------------------------------------------------------------------
// prep: weight transposes to bf16 [col][k]; W_out hi/lo; W_e -> W_eT
// f32 [hd][c] + Wehi/Welo bf16 [hd][c].
// blocks: 0-63 W_exp | 64-127 W_q | 128-255 W_kv | 256-319 W_out | 320-327 W_e
// ------------------------------------------------------------------
__global__ __launch_bounds__(256) void prep_kernel(
    const float* __restrict__ W_exp, const float* __restrict__ W_q,
    const float* __restrict__ W_kv, const float* __restrict__ W_out,
    const float* __restrict__ W_e,
    ushort* __restrict__ WT_exp, ushort* __restrict__ WT_qkv,
    ushort* __restrict__ WT_oh, ushort* __restrict__ WT_ol,
    float* __restrict__ W_eT, ushort* __restrict__ Wehi, ushort* __restrict__ Welo)
{
    __shared__ float T[64][65];
    const int id = blockIdx.x, tid = threadIdx.x;

    if (id >= 320) {            // W_e [64][512] -> W_eT f32 [512][64] + hi/lo bf16
        const int c0 = (id - 320) * 64;
        const int r = tid >> 2, cs = (tid & 3) * 16;
        #pragma unroll
        for (int e = 0; e < 4; ++e) {
            float4 x4 = *(const float4*)&W_e[(long)r * 512 + c0 + cs + e * 4];
            T[r][cs + e*4] = x4.x; T[r][cs + e*4 + 1] = x4.y;
            T[r][cs + e*4 + 2] = x4.z; T[r][cs + e*4 + 3] = x4.w;
        }
        __syncthreads();
        const int cc = tid >> 2, ks = (tid & 3) * 16;
        const int hd = c0 + cc;
        float vals[16]; ushort hs[16], ls[16];
        #pragma unroll
        for (int e = 0; e < 16; ++e) {
            vals[e] = T[ks + e][cc];
            hs[e] = f2bf(vals[e]);
            ls[e] = f2bf(vals[e] - bf2f(hs[e]));
        }
        #pragma unroll
        for (int e = 0; e < 4; ++e) {
            float4 o4; o4.x = vals[e*4]; o4.y = vals[e*4+1]; o4.z = vals[e*4+2]; o4.w = vals[e*4+3];
            *(float4*)&W_eT[(long)hd * 64 + ks + e * 4] = o4;
        }
        *(uint4*)&Wehi[(long)hd * 64 + ks]     = packu8(hs);
        *(uint4*)&Wehi[(long)hd * 64 + ks + 8] = packu8(hs + 8);
        *(uint4*)&Welo[(long)hd * 64 + ks]     = packu8(ls);
        *(uint4*)&Welo[(long)hd * 64 + ks + 8] = packu8(ls + 8);
        return;
    }
    const float* src; ushort* dst; ushort* dstl = nullptr;
    int ldS, row0, kt, ct;
    if (id < 64)       { int l = id;       kt = l >> 3; ct = l & 7;  src = W_exp; ldS = 512;  dst = WT_exp; row0 = ct * 64; }
    else if (id < 128) { int l = id - 64;  kt = l >> 3; ct = l & 7;  src = W_q;   ldS = 512;  dst = WT_qkv; row0 = ct * 64; }
    else if (id < 256) { int l = id - 128; kt = l >> 4; ct = l & 15; src = W_kv;  ldS = 1024; dst = WT_qkv; row0 = 512 + ct * 64; }
    else               { int l = id - 256; kt = l >> 3; ct = l & 7;  src = W_out; ldS = 512;  dst = WT_oh; dstl = WT_ol; row0 = ct * 64; }
    const int k0 = kt * 64, c0 = ct * 64;
    {
        const int r = tid >> 2, cs = (tid & 3) * 16;
        #pragma unroll
        for (int e = 0; e < 4; ++e) {
            float4 x4 = *(const float4*)&src[(long)(k0 + r) * ldS + c0 + cs + e * 4];
            T[r][cs + e*4] = x4.x; T[r][cs + e*4 + 1] = x4.y;
            T[r][cs + e*4 + 2] = x4.z; T[r][cs + e*4 + 3] = x4.w;
        }
    }
    __syncthreads();
    {
        const int cc = tid >> 2, ks = (tid & 3) * 16;
        float vals[16];
        #pragma unroll
        for (int e = 0; e < 16; ++e) vals[e] = T[ks + e][cc];
        ushort* d = dst + (long)(row0 + cc) * 512 + k0 + ks;
        if (!dstl) {
            *(uint4*)d = packf8(vals);
            *(uint4*)(d + 8) = packf8(vals + 8);
        } else {
            ushort hs[16], ls[16];
            #pragma unroll
            for (int e = 0; e < 16; ++e) {
                hs[e] = f2bf(vals[e]);
                ls[e] = f2bf(vals[e] - bf2f(hs[e]));
            }
            *(uint4*)d = packu8(hs);
            *(uint4*)(d + 8) = packu8(hs + 8);
            ushort* d2 = dstl + (long)(row0 + cc) * 512 + k0 + ks;
            *(uint4*)d2 = packu8(ls);
            *(uint4*)(d2 + 8) = packu8(ls + 8);
        }
    }
}

// ------------------------------------------------------------------
// bf16 MFMA GEMM. MODE 0: A=nodes f32, out x_bf bf16 (bias1).
// MODE 1: A=x_bf; blockIdx.y 0-7: q_bf[b][h][i][d] (0.125 pre-scaled,
// bias1) | 8-15: k_bf[b][h][i][d] (bias2) | 16-23: v_bf[b][hd][i]
// (transposed via LDS, bias2). All bf16 outputs.
// ------------------------------------------------------------------
template <int MODE>
__global__ __launch_bounds__(256) void gemm_v2(
    const void* __restrict__ Asrc, const ushort* __restrict__ WT,
    const float* __restrict__ bias1, const float* __restrict__ bias2,
    ushort* __restrict__ outbf, ushort* __restrict__ q_bf,
    ushort* __restrict__ k_bf, ushort* __restrict__ v_bf)
{
    __shared__ ushort As[64 * 64];
    __shared__ ushort Bs[64 * 64];
    __shared__ float  T[64][65];
    const int tid = threadIdx.x, lane = tid & 63, wid = tid >> 6;
    const int wr = wid >> 1, wc = wid & 1;
    const int bm = blockIdx.x * 64, bn = blockIdx.y * 64;
    const int srow = tid >> 2, sk = tid & 3;
    const int sw = (srow & 7) << 4;
    const int d1 = srow * 128 + ((sk * 32) ^ sw);
    const int d2 = srow * 128 + ((sk * 32 + 16) ^ sw);
    const ushort* Bsrc = WT + (long)(bn + srow) * 512 + sk * 16;

    floatx4 acc[2][2] = {};
    for (int k0 = 0; k0 < 512; k0 += 64) {
        uint4 a0, a1;
        if (MODE == 0) {
            const float* ap = (const float*)Asrc + (long)(bm + srow) * 512 + k0 + sk * 16;
            float f[16];
            #pragma unroll
            for (int e = 0; e < 4; ++e) {
                float4 x4 = *(const float4*)(ap + e * 4);
                f[e*4] = x4.x; f[e*4+1] = x4.y; f[e*4+2] = x4.z; f[e*4+3] = x4.w;
            }
            a0 = packf8(f); a1 = packf8(f + 8);
        } else {
            const ushort* ap = (const ushort*)Asrc + (long)(bm + srow) * 512 + k0 + sk * 16;
            a0 = *(const uint4*)ap; a1 = *(const uint4*)(ap + 8);
        }
        uint4 b0 = *(const uint4*)(Bsrc + k0);
        uint4 b1 = *(const uint4*)(Bsrc + k0 + 8);
        if (k0) __syncthreads();
        *(uint4*)((char*)As + d1) = a0;
        *(uint4*)((char*)As + d2) = a1;
        *(uint4*)((char*)Bs + d1) = b0;
        *(uint4*)((char*)Bs + d2) = b1;
        __syncthreads();
        #pragma unroll
        for (int s = 0; s < 2; ++s) {
            const int kb = s * 64 + ((lane >> 4) * 16);
            bf16x8 af[2], bfr[2];
            #pragma unroll
            for (int mf = 0; mf < 2; ++mf) {
                int row = wr * 32 + mf * 16 + (lane & 15);
                af[mf] = *(const bf16x8*)((const char*)As + row * 128 + (kb ^ ((row & 7) << 4)));
            }
            #pragma unroll
            for (int nf = 0; nf < 2; ++nf) {
                int col = wc * 32 + nf * 16 + (lane & 15);
                bfr[nf] = *(const bf16x8*)((const char*)Bs + col * 128 + (kb ^ ((col & 7) << 4)));
            }
            #pragma unroll
            for (int mf = 0; mf < 2; ++mf)
                #pragma unroll
                for (int nf = 0; nf < 2; ++nf)
                    acc[mf][nf] = __builtin_amdgcn_mfma_f32_16x16x32_bf16(
                        af[mf], bfr[nf], acc[mf][nf], 0, 0, 0);
        }
    }
    const int r4 = (lane >> 4) * 4, c16 = lane & 15;
    if (MODE == 0) {
        #pragma unroll
        for (int mf = 0; mf < 2; ++mf)
            #pragma unroll
            for (int nf = 0; nf < 2; ++nf)
                #pragma unroll
                for (int j = 0; j < 4; ++j) {
                    int row = bm + wr * 32 + mf * 16 + r4 + j;
                    int cn  = bn + wc * 32 + nf * 16 + c16;
                    outbf[(long)row * 512 + cn] = f2bf(acc[mf][nf][j] + bias1[cn]);
                }
    } else {
        const int cat = blockIdx.y >> 3;
        if (cat == 0) {         // q: pre-scaled bf16 [b][h][i][d]
            const int h = blockIdx.y;
            #pragma unroll
            for (int mf = 0; mf < 2; ++mf)
                #pragma unroll
                for (int nf = 0; nf < 2; ++nf)
                    #pragma unroll
                    for (int j = 0; j < 4; ++j) {
                        int row = bm + wr * 32 + mf * 16 + r4 + j;
                        int bb = row / N_, ii = row - bb * N_;
                        int d = wc * 32 + nf * 16 + c16;
                        q_bf[(((long)bb * 8 + h) * N_ + ii) * 64 + d] =
                            f2bf(0.125f * (acc[mf][nf][j] + bias1[h * 64 + d]));
                    }
        } else if (cat == 1) {  // k: bf16 [b][h][i][d]
            const int h = blockIdx.y - 8;
            #pragma unroll
            for (int mf = 0; mf < 2; ++mf)
                #pragma unroll
                for (int nf = 0; nf < 2; ++nf)
                    #pragma unroll
                    for (int j = 0; j < 4; ++j) {
                        int row = bm + wr * 32 + mf * 16 + r4 + j;
                        int bb = row / N_, ii = row - bb * N_;
                        int d = wc * 32 + nf * 16 + c16;
                        k_bf[(((long)bb * 8 + h) * N_ + ii) * 64 + d] =
                            f2bf(acc[mf][nf][j] + bias2[h * 64 + d]);
                    }
        } else {                // v: transpose via LDS -> v_bf[b][hd][i]
            #pragma unroll
            for (int mf = 0; mf < 2; ++mf)
                #pragma unroll
                for (int nf = 0; nf < 2; ++nf)
                    #pragma unroll
                    for (int j = 0; j < 4; ++j) {
                        int rl = wr * 32 + mf * 16 + r4 + j;
                        int cl = wc * 32 + nf * 16 + c16;
                        T[rl][cl] = acc[mf][nf][j] + bias2[bn - 512 + cl];
                    }
            __syncthreads();
            const int cl = tid >> 2, rl4 = (tid & 3) * 16;
            const int bb = bm / N_, ii0 = bm % N_, cv0 = bn - 1024;
            const long orow = (long)bb * 512 + cv0 + cl;
            ushort tmp[16];
            #pragma unroll
            for (int e = 0; e < 16; ++e) tmp[e] = f2bf(T[rl4 + e][cl]);
            *(uint4*)&v_bf[orow * N_ + ii0 + rl4]     = packu8(tmp);
            *(uint4*)&v_bf[orow * N_ + ii0 + rl4 + 8] = packu8(tmp + 8);
        }
    }
}

// ------------------------------------------------------------------
// K_qk: S[b,h,i,j] = q_scaled @ k^T (bf16 inputs prelaid [b][h][i][d]).
// Grid (5 i-tiles, 16 bh), 256 thr. Pure copy staging, 40 MFMAs/wave.
// ------------------------------------------------------------------
__global__ __launch_bounds__(256) void k_qk(
    const ushort* __restrict__ qbf, const ushort* __restrict__ kbf,
    float* __restrict__ S_g)
{
    __shared__ ushort Qs[64 * 64], Ks[320 * 64];
    const int it = blockIdx.x, bh = blockIdx.y;
    const int tid = threadIdx.x, lane = tid & 63, wid = tid >> 6;
    const int srow = tid >> 2, sk = tid & 3;
    const int sw = (srow & 7) << 4;
    const int d1b = ((sk * 32) ^ sw);
    const int d2b = ((sk * 32 + 16) ^ sw);

    {
        const ushort* qp = qbf + ((long)bh * N_ + it * 64 + srow) * 64 + sk * 16;
        *(uint4*)((char*)Qs + srow * 128 + d1b) = *(const uint4*)qp;
        *(uint4*)((char*)Qs + srow * 128 + d2b) = *(const uint4*)(qp + 8);
    }
    #pragma unroll
    for (int p = 0; p < 5; ++p) {
        const int row = p * 64 + srow;
        const ushort* kp = kbf + ((long)bh * N_ + row) * 64 + sk * 16;
        *(uint4*)((char*)Ks + row * 128 + d1b) = *(const uint4*)kp;
        *(uint4*)((char*)Ks + row * 128 + d2b) = *(const uint4*)(kp + 8);
    }
    __syncthreads();

    const int j0w = wid * 80;
    floatx4 acc[4][5] = {};
    #pragma unroll
    for (int s = 0; s < 2; ++s) {
        const int kb = s * 64 + ((lane >> 4) * 16);
        bf16x8 af[4], bf[5];
        #pragma unroll
        for (int mf = 0; mf < 4; ++mf) {
            int row = mf * 16 + (lane & 15);
            af[mf] = *(const bf16x8*)((const char*)Qs + row * 128 + (kb ^ ((row & 7) << 4)));
        }
        #pragma unroll
        for (int jt = 0; jt < 5; ++jt) {
            int row = j0w + jt * 16 + (lane & 15);
            bf[jt] = *(const bf16x8*)((const char*)Ks + row * 128 + (kb ^ ((row & 7) << 4)));
        }
        #pragma unroll
        for (int mf = 0; mf < 4; ++mf)
            #pragma unroll
            for (int jt = 0; jt < 5; ++jt)
                acc[mf][jt] = __builtin_amdgcn_mfma_f32_16x16x32_bf16(af[mf], bf[jt], acc[mf][jt], 0, 0, 0);
    }
    const int r4 = (lane >> 4) * 4, c16 = lane & 15;
    #pragma unroll
    for (int mf = 0; mf < 4; ++mf)
        #pragma unroll
        for (int jt = 0; jt < 5; ++jt)
            #pragma unroll
            for (int e = 0; e < 4; ++e) {
                int ri = it * 64 + mf * 16 + r4 + e;
                int cj = j0w + jt * 16 + c16;
                S_g[((long)bh * N_ + ri) * N_ + cj] = acc[mf][jt][e];
            }
}

// ------------------------------------------------------------------
// attn per (b,i): stage E bf16; t = q_bf@W_eT (VALU, 64 fma);
// S_e = t@E via MFMA (M=8 pad 16, 20 j-tiles over 8 waves) -> S_lds;
// softmax(S_lds + S_qk) -> A (bf16, LDS+global);
// U = A@E^T via MFMA (waves 0-3, 4 col-tiles... wave w = col-tile w).
// LDS: E 41472 + t 4096 + S 10240 + A 5120 = 60928 B.
// ------------------------------------------------------------------
__global__ __launch_bounds__(512) void attn_kernel(
    const ushort* __restrict__ qbf, const float* __restrict__ S_g,
    const float* __restrict__ edges, const float* __restrict__ W_eT,
    ushort* __restrict__ A_g, float* __restrict__ U_g)
{
    __shared__ ushort E_s[64 * 324];
    __shared__ float  t_lds[1024];     // [16][64], rows 8-15 zero
    __shared__ float  S_lds[8 * 320];
    __shared__ ushort A_lds[8 * 320];

    const int blk = blockIdx.x;
    const int b = blk / N_, i = blk % N_;
    const int tid = threadIdx.x;
    const int w = tid >> 6, lane = tid & 63;
    const int r16 = lane & 15, kq = (lane >> 4) * 8;

    {   // E stage
        const float* ebase = edges + (long)b * ED_ * N_ * N_ + (long)i * N_;
        for (int idx = tid; idx < 64 * 80; idx += 512) {
            int c = idx / 80, j4 = (idx % 80) * 4;
            float4 e4 = *(const float4*)(ebase + (long)c * (N_ * N_) + j4);
            uint2 pk;
            pk.x = (unsigned)f2bf(e4.x) | ((unsigned)f2bf(e4.y) << 16);
            pk.y = (unsigned)f2bf(e4.z) | ((unsigned)f2bf(e4.w) << 16);
            *(uint2*)&E_s[c * 324 + j4] = pk;
        }
    }
    {   // t[w][lane] = sum_d q_bf[b,h=w,i,d] * W_eT[w*64+d][lane]
        float tacc = 0.f;
        const ushort* qp = qbf + ((long)(b * 8 + w) * N_ + i) * 64;
        const float* wp = W_eT + (long)(w * 64) * 64 + lane;
        #pragma unroll 8
        for (int d = 0; d < 64; ++d) tacc += bf2f(qp[d]) * wp[(long)d * 64];
        t_lds[tid] = tacc;
        t_lds[512 + tid] = 0.f;
    }
    __syncthreads();

    // ---- S_e via MFMA: C[h][j] = sum_c t[h][c] * E[c][j] ----
    {
        bf16x8 ta[2];
        #pragma unroll
        for (int s = 0; s < 2; ++s) {
            const float* tp = &t_lds[r16 * 64 + s * 32 + kq];
            bf16x8 v;
            #pragma unroll
            for (int e = 0; e < 8; ++e) v[e] = (short)f2bf(tp[e]);
            ta[s] = v;
        }
        int tl[3]; int nt = 2;
        tl[0] = w * 2; tl[1] = w * 2 + 1; tl[2] = 0;
        if (w < 4) { tl[2] = 16 + w; nt = 3; }
        for (int ti = 0; ti < nt; ++ti) {
            const int j0 = tl[ti] * 16;
            floatx4 acc = {0.f, 0.f, 0.f, 0.f};
            #pragma unroll
            for (int s = 0; s < 2; ++s) {
                bf16x8 eb;
                #pragma unroll
                for (int e = 0; e < 8; ++e)
                    eb[e] = (short)E_s[(s * 32 + kq + e) * 324 + j0 + r16];
                acc = __builtin_amdgcn_mfma_f32_16x16x32_bf16(ta[s], eb, acc, 0, 0, 0);
            }
            if (lane < 32) {
                const int rr = (lane >> 4) * 4;
                #pragma unroll
                for (int jj = 0; jj < 4; ++jj)
                    S_lds[(rr + jj) * 320 + j0 + r16] = acc[jj];
            }
        }
    }
    __syncthreads();

    // ---- softmax over 320 (wave w = head w, lane j-base) ----
    const long sbase = ((long)(b * 8 + w) * N_ + i) * N_ + lane;
    float s0 = S_lds[w * 320 + lane]       + S_g[sbase];
    float s1 = S_lds[w * 320 + 64 + lane]  + S_g[sbase + 64];
    float s2 = S_lds[w * 320 + 128 + lane] + S_g[sbase + 128];
    float s3 = S_lds[w * 320 + 192 + lane] + S_g[sbase + 192];
    float s4 = S_lds[w * 320 + 256 + lane] + S_g[sbase + 256];
    float m = fmaxf(fmaxf(fmaxf(s0, s1), fmaxf(s2, s3)), s4);
    #pragma unroll
    for (int off = 32; off >= 1; off >>= 1) m = fmaxf(m, __shfl_xor(m, off, 64));
    s0 = __expf(s0 - m); s1 = __expf(s1 - m); s2 = __expf(s2 - m);
    s3 = __expf(s3 - m); s4 = __expf(s4 - m);
    float sum = s0 + s1 + s2 + s3 + s4;
    #pragma unroll
    for (int off = 32; off >= 1; off >>= 1) sum += __shfl_xor(sum, off, 64);
    float inv = 1.f / sum;
    ushort a0 = f2bf(s0 * inv), a1 = f2bf(s1 * inv), a2 = f2bf(s2 * inv),
           a3 = f2bf(s3 * inv), a4 = f2bf(s4 * inv);
    A_lds[w * 320 + lane]       = a0;
    A_lds[w * 320 + 64 + lane]  = a1;
    A_lds[w * 320 + 128 + lane] = a2;
    A_lds[w * 320 + 192 + lane] = a3;
    A_lds[w * 320 + 256 + lane] = a4;
    A_g[sbase]       = a0;
    A_g[sbase + 64]  = a1;
    A_g[sbase + 128] = a2;
    A_g[sbase + 192] = a3;
    A_g[sbase + 256] = a4;
    __syncthreads();

    // ---- U via MFMA (waves 0-3): C[h][c] = sum_j A[h][j] * E[c][j] ----
    if (w < 4) {
        const int c0 = w * 16;
        const bool rl = r16 < 8;
        const int arow = r16 & 7;
        floatx4 acc = {0.f, 0.f, 0.f, 0.f};
        #pragma unroll 2
        for (int ks = 0; ks < 10; ++ks) {
            const int jb = ks * 32 + kq;
            uint4 av = *(const uint4*)&A_lds[arow * 320 + jb];
            if (!rl) { av.x = 0; av.y = 0; av.z = 0; av.w = 0; }
            const ushort* ep = &E_s[(c0 + r16) * 324 + jb];
            uint2 e0 = *(const uint2*)ep;
            uint2 e1 = *(const uint2*)(ep + 4);
            uint4 bv; bv.x = e0.x; bv.y = e0.y; bv.z = e1.x; bv.w = e1.y;
            acc = __builtin_amdgcn_mfma_f32_16x16x32_bf16(u4bf(av), u4bf(bv), acc, 0, 0, 0);
        }
        if (lane < 32) {
            const int rr = (lane >> 4) * 4;
            #pragma unroll
            for (int jj = 0; jj < 4; ++jj)
                U_g[((long)(b * 8 + rr + jj) * N_ + i) * 64 + c0 + r16] = acc[jj];
        }
    }
}

// ------------------------------------------------------------------
// K_Ov: O = A@v_head + U@W_e_head + b_e. A,v bf16 prelaid (copy
// staging); U f32 hi/lo split; W_e hi/lo precomputed. Grid (5,16).
// ------------------------------------------------------------------
__global__ __launch_bounds__(256) void k_ov(
    const ushort* __restrict__ A_g, const ushort* __restrict__ v_bf,
    const float* __restrict__ U_g, const ushort* __restrict__ Wh_g,
    const ushort* __restrict__ Wl_g, const float* __restrict__ b_e,
    float* __restrict__ o_out)
{
    __shared__ ushort B0[64 * 64], B1[64 * 64], B2[64 * 64], B3[64 * 64];
    const int it = blockIdx.x, bh = blockIdx.y;
    const int b = bh >> 3, h = bh & 7;
    const int tid = threadIdx.x, lane = tid & 63, wid = tid >> 6;
    const int wr = wid >> 1, wc = wid & 1;
    const int srow = tid >> 2, sk = tid & 3;
    const int sw = (srow & 7) << 4;
    const int d1 = srow * 128 + ((sk * 32) ^ sw);
    const int d2 = srow * 128 + ((sk * 32 + 16) ^ sw);

    floatx4 acc[2][2] = {};
    for (int j0 = 0; j0 < 320; j0 += 64) {
        const ushort* ap = A_g + ((long)bh * N_ + it * 64 + srow) * N_ + j0 + sk * 16;
        uint4 a0 = *(const uint4*)ap, a1 = *(const uint4*)(ap + 8);
        const ushort* vp = v_bf + ((long)b * 512 + h * 64 + srow) * N_ + j0 + sk * 16;
        uint4 v0 = *(const uint4*)vp, v1 = *(const uint4*)(vp + 8);
        if (j0) __syncthreads();
        *(uint4*)((char*)B0 + d1) = a0;
        *(uint4*)((char*)B0 + d2) = a1;
        *(uint4*)((char*)B1 + d1) = v0;
        *(uint4*)((char*)B1 + d2) = v1;
        __syncthreads();
        #pragma unroll
        for (int s = 0; s < 2; ++s) {
            const int kb = s * 64 + ((lane >> 4) * 16);
            bf16x8 af[2], vh_[2];
            #pragma unroll
            for (int mf = 0; mf < 2; ++mf) {
                int row = wr * 32 + mf * 16 + (lane & 15);
                af[mf] = *(const bf16x8*)((const char*)B0 + row * 128 + (kb ^ ((row & 7) << 4)));
            }
            #pragma unroll
            for (int nf = 0; nf < 2; ++nf) {
                int col = wc * 32 + nf * 16 + (lane & 15);
                vh_[nf] = *(const bf16x8*)((const char*)B1 + col * 128 + (kb ^ ((col & 7) << 4)));
            }
            #pragma unroll
            for (int mf = 0; mf < 2; ++mf)
                #pragma unroll
                for (int nf = 0; nf < 2; ++nf)
                    acc[mf][nf] = __builtin_amdgcn_mfma_f32_16x16x32_bf16(af[mf], vh_[nf], acc[mf][nf], 0, 0, 0);
        }
    }
    // U @ W_e_head (U hi/lo x W hi/lo, 3 products)
    {
        const float* up = U_g + ((long)bh * N_ + it * 64 + srow) * 64 + sk * 16;
        float f[16]; ushort uh[16], ul[16];
        #pragma unroll
        for (int e = 0; e < 4; ++e) {
            float4 x4 = *(const float4*)(up + e * 4);
            f[e*4] = x4.x; f[e*4+1] = x4.y; f[e*4+2] = x4.z; f[e*4+3] = x4.w;
        }
        #pragma unroll
        for (int e = 0; e < 16; ++e) {
            uh[e] = f2bf(f[e]);
            ul[e] = f2bf(f[e] - bf2f(uh[e]));
        }
        const ushort* whp = Wh_g + ((long)h * 64 + srow) * 64 + sk * 16;
        const ushort* wlp = Wl_g + ((long)h * 64 + srow) * 64 + sk * 16;
        uint4 w0 = *(const uint4*)whp, w1 = *(const uint4*)(whp + 8);
        uint4 x0 = *(const uint4*)wlp, x1 = *(const uint4*)(wlp + 8);
        __syncthreads();
        *(uint4*)((char*)B0 + d1) = packu8(uh);
        *(uint4*)((char*)B0 + d2) = packu8(uh + 8);
        *(uint4*)((char*)B1 + d1) = packu8(ul);
        *(uint4*)((char*)B1 + d2) = packu8(ul + 8);
        *(uint4*)((char*)B2 + d1) = w0;
        *(uint4*)((char*)B2 + d2) = w1;
        *(uint4*)((char*)B3 + d1) = x0;
        *(uint4*)((char*)B3 + d2) = x1;
        __syncthreads();
        #pragma unroll
        for (int s = 0; s < 2; ++s) {
            const int kb = s * 64 + ((lane >> 4) * 16);
            bf16x8 ah[2], al[2], wh_[2], wl_[2];
            #pragma unroll
            for (int mf = 0; mf < 2; ++mf) {
                int row = wr * 32 + mf * 16 + (lane & 15);
                int off = row * 128 + (kb ^ ((row & 7) << 4));
                ah[mf] = *(const bf16x8*)((const char*)B0 + off);
                al[mf] = *(const bf16x8*)((const char*)B1 + off);
            }
            #pragma unroll
            for (int nf = 0; nf < 2; ++nf) {
                int col = wc * 32 + nf * 16 + (lane & 15);
                int off = col * 128 + (kb ^ ((col & 7) << 4));
                wh_[nf] = *(const bf16x8*)((const char*)B2 + off);
                wl_[nf] = *(const bf16x8*)((const char*)B3 + off);
            }
            #pragma unroll
            for (int mf = 0; mf < 2; ++mf)
                #pragma unroll
                for (int nf = 0; nf < 2; ++nf) {
                    acc[mf][nf] = __builtin_amdgcn_mfma_f32_16x16x32_bf16(ah[mf], wh_[nf], acc[mf][nf], 0, 0, 0);
                    acc[mf][nf] = __builtin_amdgcn_mfma_f32_16x16x32_bf16(al[mf], wh_[nf], acc[mf][nf], 0, 0, 0);
                    acc[mf][nf] = __builtin_amdgcn_mfma_f32_16x16x32_bf16(ah[mf], wl_[nf], acc[mf][nf], 0, 0, 0);
                }
        }
    }
    const int r4 = (lane >> 4) * 4, c16 = lane & 15;
    #pragma unroll
    for (int mf = 0; mf < 2; ++mf)
        #pragma unroll
        for (int nf = 0; nf < 2; ++nf)
            #pragma unroll
            for (int e = 0; e < 4; ++e) {
                int row = it * 64 + wr * 32 + mf * 16 + r4 + e;
                int col = wc * 32 + nf * 16 + c16;
                o_out[((long)(b * N_ + row)) * 512 + h * 64 + col] =
                    acc[mf][nf][e] + b_e[h * 64 + col];
            }
}

// ------------------------------------------------------------------
// final GEMM: out = o @ W_out + b_out, split-bf16 (~f32 accuracy).
// ------------------------------------------------------------------
__global__ __launch_bounds__(256) void gemm_out(
    const float* __restrict__ Af, const ushort* __restrict__ BTh,
    const ushort* __restrict__ BTl, const float* __restrict__ bias,
    float* __restrict__ C)
{
    __shared__ ushort Ah[64 * 64], Al[64 * 64], Bh[64 * 64], Bl[64 * 64];
    const int tid = threadIdx.x, lane = tid & 63, wid = tid >> 6;
    const int wr = wid >> 1, wc = wid & 1;
    const int bm = blockIdx.x * 64, bn = blockIdx.y * 64;
    const int srow = tid >> 2, sk = tid & 3;
    const int sw = (srow & 7) << 4;
    const int d1 = srow * 128 + ((sk * 32) ^ sw);
    const int d2 = srow * 128 + ((sk * 32 + 16) ^ sw);
    const float*  asrc = Af + (long)(bm + srow) * 512 + sk * 16;
    const ushort* bhs  = BTh + (long)(bn + srow) * 512 + sk * 16;
    const ushort* bls  = BTl + (long)(bn + srow) * 512 + sk * 16;

    floatx4 acc[2][2] = {};
    for (int k0 = 0; k0 < 512; k0 += 64) {
        float f[16];
        #pragma unroll
        for (int e = 0; e < 4; ++e) {
            float4 x4 = *(const float4*)(asrc + k0 + e * 4);
            f[e*4] = x4.x; f[e*4+1] = x4.y; f[e*4+2] = x4.z; f[e*4+3] = x4.w;
        }
        ushort hs[16], ls[16];
        #pragma unroll
        for (int e = 0; e < 16; ++e) {
            hs[e] = f2bf(f[e]);
            ls[e] = f2bf(f[e] - bf2f(hs[e]));
        }
        uint4 bh0 = *(const uint4*)(bhs + k0);
        uint4 bh1 = *(const uint4*)(bhs + k0 + 8);
        uint4 bl0 = *(const uint4*)(bls + k0);
        uint4 bl1 = *(const uint4*)(bls + k0 + 8);
        if (k0) __syncthreads();
        *(uint4*)((char*)Ah + d1) = packu8(hs);
        *(uint4*)((char*)Ah + d2) = packu8(hs + 8);
        *(uint4*)((char*)Al + d1) = packu8(ls);
        *(uint4*)((char*)Al + d2) = packu8(ls + 8);
        *(uint4*)((char*)Bh + d1) = bh0;
        *(uint4*)((char*)Bh + d2) = bh1;
        *(uint4*)((char*)Bl + d1) = bl0;
        *(uint4*)((char*)Bl + d2) = bl1;
        __syncthreads();
        #pragma unroll
        for (int s = 0; s < 2; ++s) {
            const int kb = s * 64 + ((lane >> 4) * 16);
            bf16x8 ah[2], al[2], bh[2], bl[2];
            #pragma unroll
            for (int mf = 0; mf < 2; ++mf) {
                int row = wr * 32 + mf * 16 + (lane & 15);
                int off = row * 128 + (kb ^ ((row & 7) << 4));
                ah[mf] = *(const bf16x8*)((const char*)Ah + off);
                al[mf] = *(const bf16x8*)((const char*)Al + off);
            }
            #pragma unroll
            for (int nf = 0; nf < 2; ++nf) {
                int col = wc * 32 + nf * 16 + (lane & 15);
                int off = col * 128 + (kb ^ ((col & 7) << 4));
                bh[nf] = *(const bf16x8*)((const char*)Bh + off);
                bl[nf] = *(const bf16x8*)((const char*)Bl + off);
            }
            #pragma unroll
            for (int mf = 0; mf < 2; ++mf)
                #pragma unroll
                for (int nf = 0; nf < 2; ++nf) {
                    acc[mf][nf] = __builtin_amdgcn_mfma_f32_16x16x32_bf16(ah[mf], bh[nf], acc[mf][nf], 0, 0, 0);
                    acc[mf][nf] = __builtin_amdgcn_mfma_f32_16x16x32_bf16(ah[mf], bl[nf], acc[mf][nf], 0, 0, 0);
                    acc[mf][nf] = __builtin_amdgcn_mfma_f32_16x16x32_bf16(al[mf], bh[nf], acc[mf][nf], 0, 0, 0);
                }
        }
    }
    const int r4 = (lane >> 4) * 4, c16 = lane & 15;
    #pragma unroll
    for (int mf = 0; mf < 2; ++mf)
        #pragma unroll
        for (int nf = 0; nf < 2; ++nf)
            #pragma unroll
            for (int j = 0; j < 4; ++j) {
                int row = bm + wr * 32 + mf * 16 + r4 + j;
                int col = bn + wc * 32 + nf * 16 + c16;
                C[(long)row * 512 + col] = acc[mf][nf][j] + bias[col];
            }
}

// ------------------------------------------------------------------
extern "C" void kernel_launch(void* const* d_in, const int* in_sizes, int n_in,
                              void* d_out, int out_size, void* d_ws, size_t ws_size,
                              hipStream_t stream)
{
    const float* nodes = (const float*)d_in[0];
    const float* edges = (const float*)d_in[1];
    const float* W_exp = (const float*)d_in[2];
    const float* b_exp = (const float*)d_in[3];
    const float* W_q   = (const float*)d_in[4];
    const float* b_q   = (const float*)d_in[5];
    const float* W_kv  = (const float*)d_in[6];
    const float* b_kv  = (const float*)d_in[7];
    const float* W_e   = (const float*)d_in[8];
    const float* b_e   = (const float*)d_in[9];
    const float* W_out = (const float*)d_in[10];
    const float* b_out = (const float*)d_in[11];
    float* out = (float*)d_out;

    const long SZ = (long)B_ * N_ * 512;   // 327680
    float* ws = (float*)d_ws;
    // f32 region (disjoint — fixes round-5 S_g/U_g overlap race)
    float*  S_g  = ws;                      // [16][320][320]  1,638,400
    float*  o    = ws;                      // alias S_g (S dead before k_ov)
    float*  U_g  = ws + 1638400;            // [16][320][64]     327,680
    float*  W_eT = ws + 1966080;            // [512][64]          32,768
    // bf16 region
    ushort* A_g    = (ushort*)(ws + 1998848);   // [16][320][320]
    ushort* x_bf   = A_g + 1638400;             // [640][512]
    ushort* q_bf   = x_bf + 327680;             // [2][8][320][64]
    ushort* k_bf   = q_bf + 327680;             // [2][8][320][64]
    ushort* v_bf   = k_bf + 327680;             // [2][512][320]
    ushort* WT_exp = v_bf + 327680;             // [512][512]
    ushort* WT_qkv = WT_exp + 262144;           // [1536][512]
    ushort* WT_oh  = WT_qkv + 786432;           // [512][512]
    ushort* WT_ol  = WT_oh + 262144;            // [512][512]
    ushort* Wehi   = WT_ol + 262144;            // [512][64]
    ushort* Welo   = Wehi + 32768;              // [512][64]

    // 1. weight prep
    prep_kernel<<<328, 256, 0, stream>>>(W_exp, W_q, W_kv, W_out, W_e,
                                         WT_exp, WT_qkv, WT_oh, WT_ol,
                                         W_eT, Wehi, Welo);
    // 2. x = nodes @ W_exp + b_exp (bf16)
    gemm_v2<0><<<dim3(10, 8), 256, 0, stream>>>(nodes, WT_exp, b_exp, nullptr,
                                                x_bf, nullptr, nullptr, nullptr);
    // 3. q_bf | k_bf | v_bf = x @ [W_q | W_kv] + b  (head-major bf16)
    gemm_v2<1><<<dim3(10, 24), 256, 0, stream>>>(x_bf, WT_qkv, b_q, b_kv,
                                                 nullptr, q_bf, k_bf, v_bf);
    // 4. S = q_scaled @ k^T
    k_qk<<<dim3(5, 16), 256, 0, stream>>>(q_bf, k_bf, S_g);
    // 5. fused edge softmax (MFMA S_e + U): A, U
    attn_kernel<<<640, 512, 0, stream>>>(q_bf, S_g, edges, W_eT, A_g, U_g);
    // 6. O = A@v + U@W_e + b_e
    k_ov<<<dim3(5, 16), 256, 0, stream>>>(A_g, v_bf, U_g, Wehi, Welo, b_e, o);
    // 7. out = o @ W_out + b_out
    gemm_out<<<dim3(10, 8), 256, 0, stream>>>(o, WT_oh, WT_ol, b_out, out);
}

// Round 7
// 152.274 us; speedup vs baseline: 1.6770x; 1.0678x over previous
//
#include <hip/hip_runtime.h>

// Problem constants
#define B_  2
#define N_  320
#define H_  8
#define ED_ 64

typedef __attribute__((ext_vector_type(8))) short bf16x8;
typedef __attribute__((ext_vector_type(4))) float floatx4;

__device__ __forceinline__ ushort f2bf(float f) {
    union { float f; unsigned u; } c; c.f = f;
    unsigned u = c.u;
    return (ushort)((u + 0x7fffu + ((u >> 16) & 1u)) >> 16);
}
__device__ __forceinline__ float bf2f(ushort s) {
    union { unsigned u; float f; } c; c.u = ((unsigned)s) << 16;
    return c.f;
}
__device__ __forceinline__ uint4 packf8(const float* f) {
    uint4 r;
    r.x = (unsigned)f2bf(f[0]) | ((unsigned)f2bf(f[1]) << 16);
    r.y = (unsigned)f2bf(f[2]) | ((unsigned)f2bf(f[3]) << 16);
    r.z = (unsigned)f2bf(f[4]) | ((unsigned)f2bf(f[5]) << 16);
    r.w = (unsigned)f2bf(f[6]) | ((unsigned)f2bf(f[7]) << 16);
    return r;
}
__device__ __forceinline__ uint4 packu8(const ushort* s) {
    uint4 r;
    r.x = (unsigned)s[0] | ((unsigned)s[1] << 16);
    r.y = (unsigned)s[2] | ((unsigned)s[3] << 16);
    r.z = (unsigned)s[4] | ((unsigned)s[5] << 16);
    r.w = (unsigned)s[6] | ((unsigned)s[7] << 16);
    return r;
}
__device__ __forceinline__ bf16x8 u4bf(uint4 u) {
    union { uint4 u; bf16x8 b; } c; c.u = u; return c.b;
}
// frag read from swizzled LDS tile with 128B rows
__device__ __forceinline__ bf16x8 fr(const ushort* buf, int row, int kb) {
    return *(const bf16x8*)((const char*)buf + row * 128 + (kb ^ ((row & 7) << 4)));
}

// ------------------------------------------------------------------
// prep: weight transposes to bf16 [col][k]; W_out hi/lo; W_e -> W_eT
// f32 [hd][c] + Wehi/Welo bf16 [hd][c]. (unchanged from round 6)
// ------------------------------------------------------------------
__global__ __launch_bounds__(256) void prep_kernel(
    const float* __restrict__ W_exp, const float* __restrict__ W_q,
    const float* __restrict__ W_kv, const float* __restrict__ W_out,
    const float* __restrict__ W_e,
    ushort* __restrict__ WT_exp, ushort* __restrict__ WT_qkv,
    ushort* __restrict__ WT_oh, ushort* __restrict__ WT_ol,
    float* __restrict__ W_eT, ushort* __restrict__ Wehi, ushort* __restrict__ Welo)
{
    __shared__ float T[64][65];
    const int id = blockIdx.x, tid = threadIdx.x;

    if (id >= 320) {
        const int c0 = (id - 320) * 64;
        const int r = tid >> 2, cs = (tid & 3) * 16;
        #pragma unroll
        for (int e = 0; e < 4; ++e) {
            float4 x4 = *(const float4*)&W_e[(long)r * 512 + c0 + cs + e * 4];
            T[r][cs + e*4] = x4.x; T[r][cs + e*4 + 1] = x4.y;
            T[r][cs + e*4 + 2] = x4.z; T[r][cs + e*4 + 3] = x4.w;
        }
        __syncthreads();
        const int cc = tid >> 2, ks = (tid & 3) * 16;
        const int hd = c0 + cc;
        float vals[16]; ushort hs[16], ls[16];
        #pragma unroll
        for (int e = 0; e < 16; ++e) {
            vals[e] = T[ks + e][cc];
            hs[e] = f2bf(vals[e]);
            ls[e] = f2bf(vals[e] - bf2f(hs[e]));
        }
        #pragma unroll
        for (int e = 0; e < 4; ++e) {
            float4 o4; o4.x = vals[e*4]; o4.y = vals[e*4+1]; o4.z = vals[e*4+2]; o4.w = vals[e*4+3];
            *(float4*)&W_eT[(long)hd * 64 + ks + e * 4] = o4;
        }
        *(uint4*)&Wehi[(long)hd * 64 + ks]     = packu8(hs);
        *(uint4*)&Wehi[(long)hd * 64 + ks + 8] = packu8(hs + 8);
        *(uint4*)&Welo[(long)hd * 64 + ks]     = packu8(ls);
        *(uint4*)&Welo[(long)hd * 64 + ks + 8] = packu8(ls + 8);
        return;
    }
    const float* src; ushort* dst; ushort* dstl = nullptr;
    int ldS, row0, kt, ct;
    if (id < 64)       { int l = id;       kt = l >> 3; ct = l & 7;  src = W_exp; ldS = 512;  dst = WT_exp; row0 = ct * 64; }
    else if (id < 128) { int l = id - 64;  kt = l >> 3; ct = l & 7;  src = W_q;   ldS = 512;  dst = WT_qkv; row0 = ct * 64; }
    else if (id < 256) { int l = id - 128; kt = l >> 4; ct = l & 15; src = W_kv;  ldS = 1024; dst = WT_qkv; row0 = 512 + ct * 64; }
    else               { int l = id - 256; kt = l >> 3; ct = l & 7;  src = W_out; ldS = 512;  dst = WT_oh; dstl = WT_ol; row0 = ct * 64; }
    const int k0 = kt * 64, c0 = ct * 64;
    {
        const int r = tid >> 2, cs = (tid & 3) * 16;
        #pragma unroll
        for (int e = 0; e < 4; ++e) {
            float4 x4 = *(const float4*)&src[(long)(k0 + r) * ldS + c0 + cs + e * 4];
            T[r][cs + e*4] = x4.x; T[r][cs + e*4 + 1] = x4.y;
            T[r][cs + e*4 + 2] = x4.z; T[r][cs + e*4 + 3] = x4.w;
        }
    }
    __syncthreads();
    {
        const int cc = tid >> 2, ks = (tid & 3) * 16;
        float vals[16];
        #pragma unroll
        for (int e = 0; e < 16; ++e) vals[e] = T[ks + e][cc];
        ushort* d = dst + (long)(row0 + cc) * 512 + k0 + ks;
        if (!dstl) {
            *(uint4*)d = packf8(vals);
            *(uint4*)(d + 8) = packf8(vals + 8);
        } else {
            ushort hs[16], ls[16];
            #pragma unroll
            for (int e = 0; e < 16; ++e) {
                hs[e] = f2bf(vals[e]);
                ls[e] = f2bf(vals[e] - bf2f(hs[e]));
            }
            *(uint4*)d = packu8(hs);
            *(uint4*)(d + 8) = packu8(hs + 8);
            ushort* d2 = dstl + (long)(row0 + cc) * 512 + k0 + ks;
            *(uint4*)d2 = packu8(ls);
            *(uint4*)(d2 + 8) = packu8(ls + 8);
        }
    }
}

// ------------------------------------------------------------------
// gemm_x: x_bf = bf16(nodes @ W_exp + b_exp). 32x32 tiles, grid(20,16).
// 4 waves (2x2), 1 frag/wave.
// ------------------------------------------------------------------
__global__ __launch_bounds__(256) void gemm_x(
    const float* __restrict__ A, const ushort* __restrict__ WT,
    const float* __restrict__ bias, ushort* __restrict__ xout)
{
    __shared__ ushort As[32 * 64], Bs[32 * 64];
    const int tid = threadIdx.x, lane = tid & 63, wid = tid >> 6;
    const int wr = wid >> 1, wc = wid & 1;
    const int bm = blockIdx.x * 32, bn = blockIdx.y * 32;
    const int srow = tid >> 3, sk = tid & 7;
    const int dd = srow * 128 + ((sk * 16) ^ ((srow & 7) << 4));
    const int r16 = lane & 15;

    floatx4 acc = {};
    for (int k0 = 0; k0 < 512; k0 += 64) {
        const float* ap = A + (long)(bm + srow) * 512 + k0 + sk * 8;
        float f[8];
        float4 lo = *(const float4*)ap, hi = *(const float4*)(ap + 4);
        f[0]=lo.x; f[1]=lo.y; f[2]=lo.z; f[3]=lo.w;
        f[4]=hi.x; f[5]=hi.y; f[6]=hi.z; f[7]=hi.w;
        uint4 av = packf8(f);
        uint4 bv = *(const uint4*)(WT + (long)(bn + srow) * 512 + k0 + sk * 8);
        if (k0) __syncthreads();
        *(uint4*)((char*)As + dd) = av;
        *(uint4*)((char*)Bs + dd) = bv;
        __syncthreads();
        #pragma unroll
        for (int s = 0; s < 2; ++s) {
            const int kb = s * 64 + ((lane >> 4) * 16);
            acc = __builtin_amdgcn_mfma_f32_16x16x32_bf16(
                fr(As, wr * 16 + r16, kb), fr(Bs, wc * 16 + r16, kb), acc, 0, 0, 0);
        }
    }
    const int r4 = (lane >> 4) * 4;
    #pragma unroll
    for (int j = 0; j < 4; ++j) {
        int gr = bm + wr * 16 + r4 + j;
        int gc = bn + wc * 16 + r16;
        xout[(long)gr * 512 + gc] = f2bf(acc[j] + bias[gc]);
    }
}

// ------------------------------------------------------------------
// gemm_qkv: q_bf | k_bf | v_bf = x_bf @ [W_q|W_kv] + b. 32x32 tiles,
// grid(20,48). by<16: q (0.125 pre-scaled) | <32: k | <48: v transposed.
// ------------------------------------------------------------------
__global__ __launch_bounds__(256) void gemm_qkv(
    const ushort* __restrict__ xbf, const ushort* __restrict__ WT,
    const float* __restrict__ bias1, const float* __restrict__ bias2,
    ushort* __restrict__ q_bf, ushort* __restrict__ k_bf,
    ushort* __restrict__ v_bf)
{
    __shared__ ushort As[32 * 64], Bs[32 * 64];
    __shared__ float  T[32][33];
    const int tid = threadIdx.x, lane = tid & 63, wid = tid >> 6;
    const int wr = wid >> 1, wc = wid & 1;
    const int bm = blockIdx.x * 32;
    const int cat = blockIdx.y >> 4, yy = blockIdx.y & 15;
    const int srow = tid >> 3, sk = tid & 7;
    const int dd = srow * 128 + ((sk * 16) ^ ((srow & 7) << 4));
    const int r16 = lane & 15;

    floatx4 acc = {};
    for (int k0 = 0; k0 < 512; k0 += 64) {
        uint4 av = *(const uint4*)(xbf + (long)(bm + srow) * 512 + k0 + sk * 8);
        uint4 bv = *(const uint4*)(WT + (long)(blockIdx.y * 32 + srow) * 512 + k0 + sk * 8);
        if (k0) __syncthreads();
        *(uint4*)((char*)As + dd) = av;
        *(uint4*)((char*)Bs + dd) = bv;
        __syncthreads();
        #pragma unroll
        for (int s = 0; s < 2; ++s) {
            const int kb = s * 64 + ((lane >> 4) * 16);
            acc = __builtin_amdgcn_mfma_f32_16x16x32_bf16(
                fr(As, wr * 16 + r16, kb), fr(Bs, wc * 16 + r16, kb), acc, 0, 0, 0);
        }
    }
    const int r4 = (lane >> 4) * 4;
    const int bb = bm / N_, ii0 = bm - bb * N_;
    if (cat == 0) {
        #pragma unroll
        for (int j = 0; j < 4; ++j) {
            int gr = bm + wr * 16 + r4 + j;
            int cn = yy * 32 + wc * 16 + r16;          // 0..511
            int b2 = gr / N_, ii = gr - b2 * N_;
            int h = cn >> 6, d = cn & 63;
            q_bf[(((long)b2 * 8 + h) * N_ + ii) * 64 + d] =
                f2bf(0.125f * (acc[j] + bias1[cn]));
        }
    } else if (cat == 1) {
        #pragma unroll
        for (int j = 0; j < 4; ++j) {
            int gr = bm + wr * 16 + r4 + j;
            int cn = yy * 32 + wc * 16 + r16;
            int b2 = gr / N_, ii = gr - b2 * N_;
            int h = cn >> 6, d = cn & 63;
            k_bf[(((long)b2 * 8 + h) * N_ + ii) * 64 + d] =
                f2bf(acc[j] + bias2[cn]);
        }
    } else {
        // v: transpose 32x32 tile via LDS -> v_bf[b][hd][i]
        #pragma unroll
        for (int j = 0; j < 4; ++j) {
            int cn = yy * 32 + wc * 16 + r16;
            T[wr * 16 + r4 + j][wc * 16 + r16] = acc[j] + bias2[512 + cn];
        }
        __syncthreads();
        const int dl = tid >> 3, ic = tid & 7;
        ushort tmp[4];
        #pragma unroll
        for (int e = 0; e < 4; ++e) tmp[e] = f2bf(T[ic * 4 + e][dl]);
        uint2 pk;
        pk.x = (unsigned)tmp[0] | ((unsigned)tmp[1] << 16);
        pk.y = (unsigned)tmp[2] | ((unsigned)tmp[3] << 16);
        *(uint2*)&v_bf[((long)bb * 512 + yy * 32 + dl) * N_ + ii0 + ic * 4] = pk;
    }
}

// ------------------------------------------------------------------
// k_qk: S = q_scaled @ k^T per (b,h). 64x64 tiles, grid(25,16):
// bx -> (itile=bx/5, jtile=bx%5). 4 waves 2x2, 2x2 frags each.
// ------------------------------------------------------------------
__global__ __launch_bounds__(256) void k_qk(
    const ushort* __restrict__ qbf, const ushort* __restrict__ kbf,
    float* __restrict__ S_g)
{
    __shared__ ushort Qs[64 * 64], Ks[64 * 64];
    const int itile = blockIdx.x / 5, jtile = blockIdx.x % 5;
    const int by = blockIdx.y;                 // bh
    const int i0 = itile * 64, j0 = jtile * 64;
    const int tid = threadIdx.x, lane = tid & 63, wid = tid >> 6;
    const int wr = wid >> 1, wc = wid & 1;
    const int srow = tid >> 2, sk = tid & 3;
    const int sw = (srow & 7) << 4;
    const int d1 = srow * 128 + ((sk * 32) ^ sw);
    const int d2 = srow * 128 + ((sk * 32 + 16) ^ sw);
    const int r16 = lane & 15;

    {
        const ushort* qp = qbf + ((long)by * N_ + i0 + srow) * 64 + sk * 16;
        *(uint4*)((char*)Qs + d1) = *(const uint4*)qp;
        *(uint4*)((char*)Qs + d2) = *(const uint4*)(qp + 8);
        const ushort* kp = kbf + ((long)by * N_ + j0 + srow) * 64 + sk * 16;
        *(uint4*)((char*)Ks + d1) = *(const uint4*)kp;
        *(uint4*)((char*)Ks + d2) = *(const uint4*)(kp + 8);
    }
    __syncthreads();

    floatx4 acc[2][2] = {};
    #pragma unroll
    for (int s = 0; s < 2; ++s) {
        const int kb = s * 64 + ((lane >> 4) * 16);
        bf16x8 af[2], bf[2];
        #pragma unroll
        for (int mf = 0; mf < 2; ++mf) af[mf] = fr(Qs, wr * 32 + mf * 16 + r16, kb);
        #pragma unroll
        for (int nf = 0; nf < 2; ++nf) bf[nf] = fr(Ks, wc * 32 + nf * 16 + r16, kb);
        #pragma unroll
        for (int mf = 0; mf < 2; ++mf)
            #pragma unroll
            for (int nf = 0; nf < 2; ++nf)
                acc[mf][nf] = __builtin_amdgcn_mfma_f32_16x16x32_bf16(af[mf], bf[nf], acc[mf][nf], 0, 0, 0);
    }
    const int r4 = (lane >> 4) * 4;
    #pragma unroll
    for (int mf = 0; mf < 2; ++mf)
        #pragma unroll
        for (int nf = 0; nf < 2; ++nf)
            #pragma unroll
            for (int e = 0; e < 4; ++e) {
                int ri = i0 + wr * 32 + mf * 16 + r4 + e;
                int cj = j0 + wc * 32 + nf * 16 + r16;
                S_g[((long)by * N_ + ri) * N_ + cj] = acc[mf][nf][e];
            }
}

// ------------------------------------------------------------------
// attn per (b,i): unchanged from round 6.
// ------------------------------------------------------------------
__global__ __launch_bounds__(512) void attn_kernel(
    const ushort* __restrict__ qbf, const float* __restrict__ S_g,
    const float* __restrict__ edges, const float* __restrict__ W_eT,
    ushort* __restrict__ A_g, float* __restrict__ U_g)
{
    __shared__ ushort E_s[64 * 324];
    __shared__ float  t_lds[1024];
    __shared__ float  S_lds[8 * 320];
    __shared__ ushort A_lds[8 * 320];

    const int blk = blockIdx.x;
    const int b = blk / N_, i = blk % N_;
    const int tid = threadIdx.x;
    const int w = tid >> 6, lane = tid & 63;
    const int r16 = lane & 15, kq = (lane >> 4) * 8;

    {
        const float* ebase = edges + (long)b * ED_ * N_ * N_ + (long)i * N_;
        for (int idx = tid; idx < 64 * 80; idx += 512) {
            int c = idx / 80, j4 = (idx % 80) * 4;
            float4 e4 = *(const float4*)(ebase + (long)c * (N_ * N_) + j4);
            uint2 pk;
            pk.x = (unsigned)f2bf(e4.x) | ((unsigned)f2bf(e4.y) << 16);
            pk.y = (unsigned)f2bf(e4.z) | ((unsigned)f2bf(e4.w) << 16);
            *(uint2*)&E_s[c * 324 + j4] = pk;
        }
    }
    {
        float tacc = 0.f;
        const ushort* qp = qbf + ((long)(b * 8 + w) * N_ + i) * 64;
        const float* wp = W_eT + (long)(w * 64) * 64 + lane;
        #pragma unroll 8
        for (int d = 0; d < 64; ++d) tacc += bf2f(qp[d]) * wp[(long)d * 64];
        t_lds[tid] = tacc;
        t_lds[512 + tid] = 0.f;
    }
    __syncthreads();

    {   // S_e via MFMA: C[h][j] = sum_c t[h][c] * E[c][j]
        bf16x8 ta[2];
        #pragma unroll
        for (int s = 0; s < 2; ++s) {
            const float* tp = &t_lds[r16 * 64 + s * 32 + kq];
            bf16x8 v;
            #pragma unroll
            for (int e = 0; e < 8; ++e) v[e] = (short)f2bf(tp[e]);
            ta[s] = v;
        }
        int tl[3]; int nt = 2;
        tl[0] = w * 2; tl[1] = w * 2 + 1; tl[2] = 0;
        if (w < 4) { tl[2] = 16 + w; nt = 3; }
        for (int ti = 0; ti < nt; ++ti) {
            const int j0 = tl[ti] * 16;
            floatx4 acc = {0.f, 0.f, 0.f, 0.f};
            #pragma unroll
            for (int s = 0; s < 2; ++s) {
                bf16x8 eb;
                #pragma unroll
                for (int e = 0; e < 8; ++e)
                    eb[e] = (short)E_s[(s * 32 + kq + e) * 324 + j0 + r16];
                acc = __builtin_amdgcn_mfma_f32_16x16x32_bf16(ta[s], eb, acc, 0, 0, 0);
            }
            if (lane < 32) {
                const int rr = (lane >> 4) * 4;
                #pragma unroll
                for (int jj = 0; jj < 4; ++jj)
                    S_lds[(rr + jj) * 320 + j0 + r16] = acc[jj];
            }
        }
    }
    __syncthreads();

    const long sbase = ((long)(b * 8 + w) * N_ + i) * N_ + lane;
    float s0 = S_lds[w * 320 + lane]       + S_g[sbase];
    float s1 = S_lds[w * 320 + 64 + lane]  + S_g[sbase + 64];
    float s2 = S_lds[w * 320 + 128 + lane] + S_g[sbase + 128];
    float s3 = S_lds[w * 320 + 192 + lane] + S_g[sbase + 192];
    float s4 = S_lds[w * 320 + 256 + lane] + S_g[sbase + 256];
    float m = fmaxf(fmaxf(fmaxf(s0, s1), fmaxf(s2, s3)), s4);
    #pragma unroll
    for (int off = 32; off >= 1; off >>= 1) m = fmaxf(m, __shfl_xor(m, off, 64));
    s0 = __expf(s0 - m); s1 = __expf(s1 - m); s2 = __expf(s2 - m);
    s3 = __expf(s3 - m); s4 = __expf(s4 - m);
    float sum = s0 + s1 + s2 + s3 + s4;
    #pragma unroll
    for (int off = 32; off >= 1; off >>= 1) sum += __shfl_xor(sum, off, 64);
    float inv = 1.f / sum;
    ushort a0 = f2bf(s0 * inv), a1 = f2bf(s1 * inv), a2 = f2bf(s2 * inv),
           a3 = f2bf(s3 * inv), a4 = f2bf(s4 * inv);
    A_lds[w * 320 + lane]       = a0;
    A_lds[w * 320 + 64 + lane]  = a1;
    A_lds[w * 320 + 128 + lane] = a2;
    A_lds[w * 320 + 192 + lane] = a3;
    A_lds[w * 320 + 256 + lane] = a4;
    A_g[sbase]       = a0;
    A_g[sbase + 64]  = a1;
    A_g[sbase + 128] = a2;
    A_g[sbase + 192] = a3;
    A_g[sbase + 256] = a4;
    __syncthreads();

    if (w < 4) {
        const int c0 = w * 16;
        const bool rl = r16 < 8;
        const int arow = r16 & 7;
        floatx4 acc = {0.f, 0.f, 0.f, 0.f};
        #pragma unroll 2
        for (int ks = 0; ks < 10; ++ks) {
            const int jb = ks * 32 + kq;
            uint4 av = *(const uint4*)&A_lds[arow * 320 + jb];
            if (!rl) { av.x = 0; av.y = 0; av.z = 0; av.w = 0; }
            const ushort* ep = &E_s[(c0 + r16) * 324 + jb];
            uint2 e0 = *(const uint2*)ep;
            uint2 e1 = *(const uint2*)(ep + 4);
            uint4 bv; bv.x = e0.x; bv.y = e0.y; bv.z = e1.x; bv.w = e1.y;
            acc = __builtin_amdgcn_mfma_f32_16x16x32_bf16(u4bf(av), u4bf(bv), acc, 0, 0, 0);
        }
        if (lane < 32) {
            const int rr = (lane >> 4) * 4;
            #pragma unroll
            for (int jj = 0; jj < 4; ++jj)
                U_g[((long)(b * 8 + rr + jj) * N_ + i) * 64 + c0 + r16] = acc[jj];
        }
    }
}

// ------------------------------------------------------------------
// k_ov: O = A@v_head + U@W_e_head + b_e, emitted as hi/lo bf16.
// 16-row i-tiles, grid(20,16). 4 waves, wave w = cols w*16..w*16+15.
// ------------------------------------------------------------------
__global__ __launch_bounds__(256) void k_ov(
    const ushort* __restrict__ A_g, const ushort* __restrict__ v_bf,
    const float* __restrict__ U_g, const ushort* __restrict__ Wh_g,
    const ushort* __restrict__ Wl_g, const float* __restrict__ b_e,
    ushort* __restrict__ oh_g, ushort* __restrict__ ol_g)
{
    __shared__ ushort Aa[16 * 64], Vv[64 * 64];
    __shared__ ushort Uh[16 * 64], Ul[16 * 64], Wh[64 * 64], Wl[64 * 64];
    const int i0 = blockIdx.x * 16, by = blockIdx.y;   // by = bh
    const int b = by >> 3, h = by & 7;
    const int tid = threadIdx.x, lane = tid & 63, w = tid >> 6;
    const int r16 = lane & 15;
    const int srow4 = tid >> 2, sk4 = tid & 3;
    const int sw4 = (srow4 & 7) << 4;
    const int d1 = srow4 * 128 + ((sk4 * 32) ^ sw4);
    const int d2 = srow4 * 128 + ((sk4 * 32 + 16) ^ sw4);
    const int srow8 = tid >> 3, sk8 = tid & 7;
    const int dd16 = srow8 * 128 + ((sk8 * 16) ^ ((srow8 & 7) << 4));

    // one-time staging: U (hi/lo) and W_e (hi/lo)
    if (tid < 128) {
        const float* up = U_g + ((long)by * N_ + i0 + srow8) * 64 + sk8 * 8;
        float f[8];
        float4 lo = *(const float4*)up, hi = *(const float4*)(up + 4);
        f[0]=lo.x; f[1]=lo.y; f[2]=lo.z; f[3]=lo.w;
        f[4]=hi.x; f[5]=hi.y; f[6]=hi.z; f[7]=hi.w;
        ushort uh[8], ul[8];
        #pragma unroll
        for (int e = 0; e < 8; ++e) {
            uh[e] = f2bf(f[e]);
            ul[e] = f2bf(f[e] - bf2f(uh[e]));
        }
        *(uint4*)((char*)Uh + dd16) = packu8(uh);
        *(uint4*)((char*)Ul + dd16) = packu8(ul);
    }
    {
        const ushort* whp = Wh_g + ((long)h * 64 + srow4) * 64 + sk4 * 16;
        *(uint4*)((char*)Wh + d1) = *(const uint4*)whp;
        *(uint4*)((char*)Wh + d2) = *(const uint4*)(whp + 8);
        const ushort* wlp = Wl_g + ((long)h * 64 + srow4) * 64 + sk4 * 16;
        *(uint4*)((char*)Wl + d1) = *(const uint4*)wlp;
        *(uint4*)((char*)Wl + d2) = *(const uint4*)(wlp + 8);
    }

    floatx4 acc = {};
    for (int j0 = 0; j0 < 320; j0 += 64) {
        uint4 av; 
        if (tid < 128)
            av = *(const uint4*)(A_g + ((long)by * N_ + i0 + srow8) * N_ + j0 + sk8 * 8);
        const ushort* vp = v_bf + ((long)b * 512 + h * 64 + srow4) * N_ + j0 + sk4 * 16;
        uint4 v0 = *(const uint4*)vp, v1 = *(const uint4*)(vp + 8);
        if (j0) __syncthreads();
        if (tid < 128) *(uint4*)((char*)Aa + dd16) = av;
        *(uint4*)((char*)Vv + d1) = v0;
        *(uint4*)((char*)Vv + d2) = v1;
        __syncthreads();
        #pragma unroll
        for (int s = 0; s < 2; ++s) {
            const int kb = s * 64 + ((lane >> 4) * 16);
            acc = __builtin_amdgcn_mfma_f32_16x16x32_bf16(
                fr(Aa, r16, kb), fr(Vv, w * 16 + r16, kb), acc, 0, 0, 0);
        }
    }
    // U @ W_e (staged before first sync; still valid)
    #pragma unroll
    for (int s = 0; s < 2; ++s) {
        const int kb = s * 64 + ((lane >> 4) * 16);
        bf16x8 ah = fr(Uh, r16, kb), al = fr(Ul, r16, kb);
        bf16x8 wh = fr(Wh, w * 16 + r16, kb), wl = fr(Wl, w * 16 + r16, kb);
        acc = __builtin_amdgcn_mfma_f32_16x16x32_bf16(ah, wh, acc, 0, 0, 0);
        acc = __builtin_amdgcn_mfma_f32_16x16x32_bf16(al, wh, acc, 0, 0, 0);
        acc = __builtin_amdgcn_mfma_f32_16x16x32_bf16(ah, wl, acc, 0, 0, 0);
    }
    const int r4 = (lane >> 4) * 4;
    #pragma unroll
    for (int e = 0; e < 4; ++e) {
        int row = b * N_ + i0 + r4 + e;
        int col = h * 64 + w * 16 + r16;
        float val = acc[e] + b_e[col];
        ushort vh = f2bf(val);
        ushort vl = f2bf(val - bf2f(vh));
        oh_g[(long)row * 512 + col] = vh;
        ol_g[(long)row * 512 + col] = vl;
    }
}

// ------------------------------------------------------------------
// gemm_out: out = o @ W_out + b_out via split-bf16 (3 products).
// A = oh/ol (pre-split), B = WT_oh/ol. 32x32 tiles, grid(20,16).
// ------------------------------------------------------------------
__global__ __launch_bounds__(256) void gemm_out(
    const ushort* __restrict__ oh, const ushort* __restrict__ ol,
    const ushort* __restrict__ BTh, const ushort* __restrict__ BTl,
    const float* __restrict__ bias, float* __restrict__ C)
{
    __shared__ ushort Ah[32 * 64], Al[32 * 64], Bh[32 * 64], Bl[32 * 64];
    const int tid = threadIdx.x, lane = tid & 63, wid = tid >> 6;
    const int wr = wid >> 1, wc = wid & 1;
    const int bm = blockIdx.x * 32, bn = blockIdx.y * 32;
    const int srow = tid >> 3, sk = tid & 7;
    const int dd = srow * 128 + ((sk * 16) ^ ((srow & 7) << 4));
    const int r16 = lane & 15;

    floatx4 acc = {};
    for (int k0 = 0; k0 < 512; k0 += 64) {
        const long arow = (long)(bm + srow) * 512 + k0 + sk * 8;
        uint4 a0 = *(const uint4*)(oh + arow);
        uint4 a1 = *(const uint4*)(ol + arow);
        const long brow = (long)(bn + srow) * 512 + k0 + sk * 8;
        uint4 b0 = *(const uint4*)(BTh + brow);
        uint4 b1 = *(const uint4*)(BTl + brow);
        if (k0) __syncthreads();
        *(uint4*)((char*)Ah + dd) = a0;
        *(uint4*)((char*)Al + dd) = a1;
        *(uint4*)((char*)Bh + dd) = b0;
        *(uint4*)((char*)Bl + dd) = b1;
        __syncthreads();
        #pragma unroll
        for (int s = 0; s < 2; ++s) {
            const int kb = s * 64 + ((lane >> 4) * 16);
            bf16x8 ah = fr(Ah, wr * 16 + r16, kb), al = fr(Al, wr * 16 + r16, kb);
            bf16x8 bh = fr(Bh, wc * 16 + r16, kb), bl = fr(Bl, wc * 16 + r16, kb);
            acc = __builtin_amdgcn_mfma_f32_16x16x32_bf16(ah, bh, acc, 0, 0, 0);
            acc = __builtin_amdgcn_mfma_f32_16x16x32_bf16(ah, bl, acc, 0, 0, 0);
            acc = __builtin_amdgcn_mfma_f32_16x16x32_bf16(al, bh, acc, 0, 0, 0);
        }
    }
    const int r4 = (lane >> 4) * 4;
    #pragma unroll
    for (int j = 0; j < 4; ++j) {
        int gr = bm + wr * 16 + r4 + j;
        int gc = bn + wc * 16 + r16;
        C[(long)gr * 512 + gc] = acc[j] + bias[gc];
    }
}

// ------------------------------------------------------------------
extern "C" void kernel_launch(void* const* d_in, const int* in_sizes, int n_in,
                              void* d_out, int out_size, void* d_ws, size_t ws_size,
                              hipStream_t stream)
{
    const float* nodes = (const float*)d_in[0];
    const float* edges = (const float*)d_in[1];
    const float* W_exp = (const float*)d_in[2];
    const float* b_exp = (const float*)d_in[3];
    const float* W_q   = (const float*)d_in[4];
    const float* b_q   = (const float*)d_in[5];
    const float* W_kv  = (const float*)d_in[6];
    const float* b_kv  = (const float*)d_in[7];
    const float* W_e   = (const float*)d_in[8];
    const float* b_e   = (const float*)d_in[9];
    const float* W_out = (const float*)d_in[10];
    const float* b_out = (const float*)d_in[11];
    float* out = (float*)d_out;

    float* ws = (float*)d_ws;
    float*  S_g  = ws;                          // [16][320][320] f32
    float*  U_g  = ws + 1638400;                // [16][320][64]  f32
    float*  W_eT = ws + 1966080;                // [512][64]      f32
    ushort* A_g    = (ushort*)(ws + 1998848);   // [16][320][320] bf16
    ushort* x_bf   = A_g + 1638400;             // [640][512]
    ushort* q_bf   = x_bf + 327680;             // [2][8][320][64]
    ushort* k_bf   = q_bf + 327680;             // [2][8][320][64]
    ushort* v_bf   = k_bf + 327680;             // [2][512][320]
    ushort* oh_g   = v_bf + 327680;             // [640][512]
    ushort* ol_g   = oh_g + 327680;             // [640][512]
    ushort* WT_exp = ol_g + 327680;             // [512][512]
    ushort* WT_qkv = WT_exp + 262144;           // [1536][512]
    ushort* WT_oh  = WT_qkv + 786432;           // [512][512]
    ushort* WT_ol  = WT_oh + 262144;            // [512][512]
    ushort* Wehi   = WT_ol + 262144;            // [512][64]
    ushort* Welo   = Wehi + 32768;              // [512][64]

    prep_kernel<<<328, 256, 0, stream>>>(W_exp, W_q, W_kv, W_out, W_e,
                                         WT_exp, WT_qkv, WT_oh, WT_ol,
                                         W_eT, Wehi, Welo);
    gemm_x<<<dim3(20, 16), 256, 0, stream>>>(nodes, WT_exp, b_exp, x_bf);
    gemm_qkv<<<dim3(20, 48), 256, 0, stream>>>(x_bf, WT_qkv, b_q, b_kv,
                                               q_bf, k_bf, v_bf);
    k_qk<<<dim3(25, 16), 256, 0, stream>>>(q_bf, k_bf, S_g);
    attn_kernel<<<640, 512, 0, stream>>>(q_bf, S_g, edges, W_eT, A_g, U_g);
    k_ov<<<dim3(20, 16), 256, 0, stream>>>(A_g, v_bf, U_g, Wehi, Welo, b_e,
                                           oh_g, ol_g);
    gemm_out<<<dim3(20, 16), 256, 0, stream>>>(oh_g, ol_g, WT_oh, WT_ol, b_out, out);
}